// Round 5
// baseline (222.786 us; speedup 1.0000x reference)
//
#include <hip/hip_runtime.h>
#include <cstdint>

#define NN 1024
#define BB 32
#define LL 128
#define DE 16
#define HH 4
#define K1 4
#define BD 512
#define NS 524288   // NN*BD, floats per head slab

using bf16x8 = __attribute__((ext_vector_type(8))) short;
using f32x4  = __attribute__((ext_vector_type(4))) float;

__device__ inline unsigned short f2bf(float f) {
    unsigned u = __builtin_bit_cast(unsigned, f);
    u += 0x7FFFu + ((u >> 16) & 1u);          // round-to-nearest-even
    return (unsigned short)(u >> 16);
}

// ---------------------------------------------------------------- Q/K projections
__global__ __launch_bounds__(256) void qk_kernel(
    const float* __restrict__ psi_emb, const float* __restrict__ W_q,
    const float* __restrict__ W_k, float* __restrict__ Qbuf, float* __restrict__ Kbuf)
{
    const int idx = blockIdx.x * 256 + threadIdx.x;   // N*H*DE = 65536
    const int n = idx >> 6;
    const int hm = idx & 63;
    const float* e = psi_emb + n * DE;
    float q = 0.f, k = 0.f;
#pragma unroll
    for (int d = 0; d < DE; d++) {
        const float ev = e[d];
        q += ev * W_q[d * 64 + hm];
        k += ev * W_k[d * 64 + hm];
    }
    Qbuf[idx] = q;
    Kbuf[idx] = k;
}

// ---------------------------------------------------------------- blended adjacency -> At (bf16, fragment-tiled)
// At element (h, i, j) at h*1048576 + (j>>3)*8192 + i*8 + (j&7).
// R4 post-mortem: old version spent ~80 __syncthreads in 5 LDS tree reductions
// (VALUBusy 14%, 43 us). Now: numerators live in registers (4 j's/thread),
// wave shfl_xor butterfly + single 4x5 partial combine = 2 barriers total,
// native __expf, Qi/e_i in broadcast registers (no LDS in the hot loop).
__global__ __launch_bounds__(256) void adj_kernel(
    const float* __restrict__ psi_emb, const float* __restrict__ psi_p,
    const float* __restrict__ alpha_p, const float* __restrict__ Qbuf,
    const float* __restrict__ Kbuf, short* __restrict__ At)
{
    __shared__ float partial[4][5];

    const int i = blockIdx.x;
    const int tid = threadIdx.x;
    const int wave = tid >> 6, lane = tid & 63;

    // broadcast loads (all lanes same address -> L1 broadcast)
    float er[DE];
#pragma unroll
    for (int d = 0; d < DE; d += 4) {
        const float4 v = *(const float4*)(psi_emb + i * DE + d);
        er[d] = v.x; er[d + 1] = v.y; er[d + 2] = v.z; er[d + 3] = v.w;
    }
    float qr[64];
#pragma unroll
    for (int d = 0; d < 64; d += 4) {
        const float4 v = *(const float4*)(Qbuf + i * 64 + d);
        qr[d] = v.x; qr[d + 1] = v.y; qr[d + 2] = v.z; qr[d + 3] = v.w;
    }

    const float psi = psi_p[0];
    float bn[4], an[4][HH];
    float sb = 0.f, sa[HH] = {0.f, 0.f, 0.f, 0.f};
#pragma unroll
    for (int it = 0; it < 4; it++) {
        const int j = tid + it * 256;
        const float* ej = psi_emb + j * DE;
        float d2 = 0.f;
#pragma unroll
        for (int d = 0; d < DE; d++) { const float t = er[d] - ej[d]; d2 += t * t; }
        const float bnum = __expf(__expf(-psi * d2));
        bn[it] = bnum;
        sb += bnum;
        const float* kj = Kbuf + j * 64;
#pragma unroll
        for (int h = 0; h < HH; h++) {
            float dot = 0.f;
#pragma unroll
            for (int m = 0; m < DE; m++) dot += qr[h * DE + m] * kj[h * DE + m];
            const float a = __expf(dot * 0.25f);
            an[it][h] = a;
            sa[h] += a;
        }
    }
    // wave butterfly reduction (deterministic)
#pragma unroll
    for (int s = 32; s > 0; s >>= 1) {
        sb += __shfl_xor(sb, s, 64);
#pragma unroll
        for (int h = 0; h < HH; h++) sa[h] += __shfl_xor(sa[h], s, 64);
    }
    if (lane == 0) {
        partial[wave][0] = sb;
#pragma unroll
        for (int h = 0; h < HH; h++) partial[wave][1 + h] = sa[h];
    }
    __syncthreads();
    const float S0 = partial[0][0] + partial[1][0] + partial[2][0] + partial[3][0];
    float Sh[HH];
#pragma unroll
    for (int h = 0; h < HH; h++)
        Sh[h] = partial[0][1 + h] + partial[1][1 + h] + partial[2][1 + h] + partial[3][1 + h];

    const float alpha = 1.f / (1.f + __expf(-alpha_p[0]));
    const float ib = alpha / S0;
    float ia[HH];
#pragma unroll
    for (int h = 0; h < HH; h++) ia[h] = (1.f - alpha) / Sh[h];

#pragma unroll
    for (int it = 0; it < 4; it++) {
        const int j = tid + it * 256;
        const float b = bn[it] * ib;
        const size_t base = (size_t)(j >> 3) * 8192 + (size_t)i * 8 + (j & 7);
#pragma unroll
        for (int h = 0; h < HH; h++)
            At[(size_t)h * 1048576 + base] = (short)f2bf(b + an[it][h] * ia[h]);
    }
}

// ---------------------------------------------------------------- x -> xt (bf16, A-fragment-tiled per b)
// xt element (b, m, l) at b*131072 + (l>>3)*8192 + m*8 + (l&7)
__global__ __launch_bounds__(256) void xt_cast(
    const float* __restrict__ x, short* __restrict__ xt)
{
    const int m0 = blockIdx.x * 64;
    const int b  = blockIdx.y;
    __shared__ float xs[64][128];
    const int tid = threadIdx.x;
    for (int i = tid; i < 2048; i += 256) {           // 2048 float4s
        const int row = i >> 5, lq = i & 31;
        *(float4*)&xs[row][lq * 4] =
            *(const float4*)(x + ((size_t)(b * NN + m0 + row)) * LL + lq * 4);
    }
    __syncthreads();
    for (int j = tid; j < 1024; j += 256) {
        const int m = j & 63, lc = j >> 6;
        const float* s = &xs[m][lc * 8];
        uint4 pk;
        pk.x = f2bf(s[0]) | ((unsigned)f2bf(s[1]) << 16);
        pk.y = f2bf(s[2]) | ((unsigned)f2bf(s[3]) << 16);
        pk.z = f2bf(s[4]) | ((unsigned)f2bf(s[5]) << 16);
        pk.w = f2bf(s[6]) | ((unsigned)f2bf(s[7]) << 16);
        *(uint4*)(xt + (size_t)b * 131072 + (size_t)lc * 8192 + (size_t)(m0 + m) * 8) = pk;
    }
}

// ---------------------------------------------------------------- F_w -> wtt (bf16, B-fragment-tiled)
// wtt element (l, c) at (l>>3)*2048 + c*8 + (l&7), c = (h*4+k)*16+d
__global__ __launch_bounds__(256) void wtt_cast(
    const float* __restrict__ F_w, short* __restrict__ wtt)
{
    const int j = blockIdx.x * 256 + threadIdx.x;     // 16*256
    const int lc = j >> 8, c = j & 255;
    const int h = c >> 6, k = (c >> 4) & 3, d = c & 15;
    const float* s = F_w + (size_t)((h * DE + d) * K1 + k) * LL + lc * 8;
    uint4 pk;
    pk.x = f2bf(s[0]) | ((unsigned)f2bf(s[1]) << 16);
    pk.y = f2bf(s[2]) | ((unsigned)f2bf(s[3]) << 16);
    pk.z = f2bf(s[4]) | ((unsigned)f2bf(s[5]) << 16);
    pk.w = f2bf(s[6]) | ((unsigned)f2bf(s[7]) << 16);
    *(uint4*)(wtt + (size_t)lc * 2048 + (size_t)c * 8) = pk;
}

// ---------------------------------------------------------------- G stage (MFMA, K=128, registers only)
__global__ __launch_bounds__(256) void g_mfma(
    const short* __restrict__ xt, const short* __restrict__ wtt,
    float* __restrict__ Gs, short* __restrict__ g3t)
{
    const int cb = blockIdx.x;           // 0..3  (64 cols)
    const int m0 = blockIdx.y * 64;      // 0..15
    const int bp = blockIdx.z;           // 0..15 (b pair)
    const int tid = threadIdx.x;
    const int wave = tid >> 6, lane = tid & 63;
    const int b  = bp * 2 + (wave >> 1);
    const int wc = wave & 1;
    const int q = lane >> 4, m16 = lane & 15;
    const short* xb = xt + (size_t)b * 131072;

    f32x4 acc[4][2];
#pragma unroll
    for (int mi = 0; mi < 4; mi++)
#pragma unroll
        for (int ni = 0; ni < 2; ni++) acc[mi][ni] = (f32x4){0.f, 0.f, 0.f, 0.f};

#pragma unroll
    for (int ks = 0; ks < 4; ks++) {
        const int kc = ks * 4 + q;
        bf16x8 a[4], bb[2];
#pragma unroll
        for (int mi = 0; mi < 4; mi++)
            a[mi] = *(const bf16x8*)(xb + (size_t)kc * 8192 + (size_t)(m0 + mi * 16 + m16) * 8);
#pragma unroll
        for (int ni = 0; ni < 2; ni++)
            bb[ni] = *(const bf16x8*)(wtt + (size_t)kc * 2048 +
                                      (size_t)(cb * 64 + wc * 32 + ni * 16 + m16) * 8);
#pragma unroll
        for (int mi = 0; mi < 4; mi++)
#pragma unroll
            for (int ni = 0; ni < 2; ni++)
                acc[mi][ni] = __builtin_amdgcn_mfma_f32_16x16x32_bf16(a[mi], bb[ni], acc[mi][ni], 0, 0, 0);
    }

#pragma unroll
    for (int ni = 0; ni < 2; ni++) {
        const int cc = cb * 64 + wc * 32 + ni * 16 + m16;
        const int kk = (cc >> 4) & 3, hh = cc >> 6;
        const int slab = kk * 4 + hh;
        const int col512 = b * 16 + (cc & 15);
        float* gdst = Gs + (size_t)slab * NS;
#pragma unroll
        for (int mi = 0; mi < 4; mi++) {
            const int row0 = m0 + mi * 16 + q * 4;
#pragma unroll
            for (int r = 0; r < 4; r++)
                gdst[(size_t)(row0 + r) * BD + col512] = acc[mi][ni][r];
            if (kk == 3) {
                ushort4 pk;
                pk.x = f2bf(acc[mi][ni][0]); pk.y = f2bf(acc[mi][ni][1]);
                pk.z = f2bf(acc[mi][ni][2]); pk.w = f2bf(acc[mi][ni][3]);
                *(ushort4*)(g3t + (size_t)hh * 524288 +
                            ((size_t)(row0 >> 3) * 512 + col512) * 8 + (row0 & 7)) = pk;
            }
        }
    }
}

// ---------------------------------------------------------------- Clenshaw GEMM (MFMA)
__global__ __launch_bounds__(256) void gemm_mf(
    const short* __restrict__ At, const short* __restrict__ Bt,
    const float* __restrict__ P, const float* __restrict__ Q,
    float* __restrict__ O, short* __restrict__ Ot,
    float scale, float pc, float qc, int writeO, int writeOt)
{
    const int h = blockIdx.z;
    const short* Ah = At + (size_t)h * 1048576;
    const short* Bh = Bt + (size_t)h * 524288;
    const float* Ph = P + (size_t)h * NS;
    const float* Qh = Q + (size_t)h * NS;
    float* Oh = O + (size_t)h * NS;
    short* Oth = Ot + (size_t)h * 524288;

    const int c0 = blockIdx.x * 64;
    const int r0 = blockIdx.y * 64;
    const int tid = threadIdx.x;
    const int wave = tid >> 6, lane = tid & 63;
    const int q = lane >> 4, m16 = lane & 15;
    const int wr = wave >> 1, wc = wave & 1;

    __shared__ __align__(16) short As[2][2048];
    __shared__ __align__(16) short Bs[2][2048];

    {
        uint4 ra = *(const uint4*)(Ah + ((size_t)wave * 1024 + r0 + lane) * 8);
        uint4 rb = *(const uint4*)(Bh + ((size_t)wave * 512 + c0 + lane) * 8);
        *(uint4*)&As[0][wave * 512 + lane * 8] = ra;
        *(uint4*)&Bs[0][wave * 512 + lane * 8] = rb;
    }
    __syncthreads();

    f32x4 acc[2][2];
#pragma unroll
    for (int mi = 0; mi < 2; mi++)
#pragma unroll
        for (int ni = 0; ni < 2; ni++) acc[mi][ni] = (f32x4){0.f, 0.f, 0.f, 0.f};

    int buf = 0;
    for (int k0 = 32; k0 <= 1024; k0 += 32) {
        uint4 na, nb;
        const bool more = (k0 < 1024);
        if (more) {
            na = *(const uint4*)(Ah + (((size_t)(k0 >> 3) + wave) * 1024 + r0 + lane) * 8);
            nb = *(const uint4*)(Bh + (((size_t)(k0 >> 3) + wave) * 512 + c0 + lane) * 8);
        }
        bf16x8 af0 = *(const bf16x8*)&As[buf][q * 512 + (wr * 32 + m16) * 8];
        bf16x8 af1 = *(const bf16x8*)&As[buf][q * 512 + (wr * 32 + 16 + m16) * 8];
        bf16x8 bf0 = *(const bf16x8*)&Bs[buf][q * 512 + (wc * 32 + m16) * 8];
        bf16x8 bf1 = *(const bf16x8*)&Bs[buf][q * 512 + (wc * 32 + 16 + m16) * 8];
        acc[0][0] = __builtin_amdgcn_mfma_f32_16x16x32_bf16(af0, bf0, acc[0][0], 0, 0, 0);
        acc[0][1] = __builtin_amdgcn_mfma_f32_16x16x32_bf16(af0, bf1, acc[0][1], 0, 0, 0);
        acc[1][0] = __builtin_amdgcn_mfma_f32_16x16x32_bf16(af1, bf0, acc[1][0], 0, 0, 0);
        acc[1][1] = __builtin_amdgcn_mfma_f32_16x16x32_bf16(af1, bf1, acc[1][1], 0, 0, 0);
        if (more) {
            const int nx = buf ^ 1;
            *(uint4*)&As[nx][wave * 512 + lane * 8] = na;
            *(uint4*)&Bs[nx][wave * 512 + lane * 8] = nb;
            __syncthreads();
            buf = nx;
        }
    }

#pragma unroll
    for (int mi = 0; mi < 2; mi++) {
        const int row0 = r0 + wr * 32 + mi * 16 + q * 4;
#pragma unroll
        for (int ni = 0; ni < 2; ni++) {
            const int cc = c0 + wc * 32 + ni * 16 + m16;
            float v[4];
#pragma unroll
            for (int r = 0; r < 4; r++) {
                const size_t off = (size_t)(row0 + r) * BD + cc;
                float t = scale * acc[mi][ni][r] + pc * Ph[off];
                if (qc != 0.f) t += qc * Qh[off];
                v[r] = t;
                if (writeO) Oh[off] = t;
            }
            if (writeOt) {
                ushort4 pk;
                pk.x = f2bf(v[0]); pk.y = f2bf(v[1]); pk.z = f2bf(v[2]); pk.w = f2bf(v[3]);
                *(ushort4*)(Oth + ((size_t)(row0 >> 3) * 512 + cc) * 8 + (row0 & 7)) = pk;
            }
        }
    }
}

// ---------------------------------------------------------------- final contraction
__global__ __launch_bounds__(256) void out_kernel(
    const float* __restrict__ psi_emb, const float* __restrict__ f_b,
    const float* __restrict__ head_mix, const float* __restrict__ S,
    float* __restrict__ out)
{
    const int id = blockIdx.x * 256 + threadIdx.x;  // id = b*N + n
    const int n = id & (NN - 1);
    const int b = id >> 10;
    const float hm0 = head_mix[0], hm1 = head_mix[1], hm2 = head_mix[2], hm3 = head_mix[3];
    const float mx = fmaxf(fmaxf(hm0, hm1), fmaxf(hm2, hm3));
    const float w0 = expf(hm0 - mx), w1 = expf(hm1 - mx), w2 = expf(hm2 - mx), w3 = expf(hm3 - mx);
    const float isum = 1.f / (w0 + w1 + w2 + w3);
    const float mw[4] = {w0 * isum, w1 * isum, w2 * isum, w3 * isum};
    float e[DE];
#pragma unroll
    for (int d = 0; d < DE; d++) e[d] = psi_emb[n * DE + d];
    float total = 0.f;
#pragma unroll
    for (int h = 0; h < HH; h++) {
        const float* sp = S + ((size_t)h * NN + n) * BD + b * DE;
        const float* fb = f_b + h * DE;
        float acc = 0.f;
#pragma unroll
        for (int d = 0; d < DE; d++) acc += e[d] * (sp[d] + fb[d]);
        total += mw[h] * acc;
    }
    out[id] = total;
}

extern "C" void kernel_launch(void* const* d_in, const int* in_sizes, int n_in,
                              void* d_out, int out_size, void* d_ws, size_t ws_size,
                              hipStream_t stream)
{
    const float* x          = (const float*)d_in[0];
    const float* psi_emb    = (const float*)d_in[1];
    const float* psi        = (const float*)d_in[2];
    const float* W_q        = (const float*)d_in[3];
    const float* W_k        = (const float*)d_in[4];
    const float* attn_alpha = (const float*)d_in[5];
    const float* F_w        = (const float*)d_in[6];
    const float* f_b        = (const float*)d_in[7];
    const float* head_mix   = (const float*)d_in[8];
    float* out = (float*)d_out;

    short* At  = (short*)d_ws;                 // 4,194,304 bf16 (tiled, per-h 1,048,576)
    short* xt  = At + 4194304;                 // 4,194,304
    short* wtt = xt + 4194304;                 // 32,768
    short* g3t = wtt + 32768;                  // 2,097,152 (per-h 524,288)
    short* b2t = g3t + 2097152;                // 2,097,152
    short* b1t = b2t + 2097152;                // 2,097,152
    float* Gs  = (float*)(b1t + 2097152);      // 16 slabs (k*4+h) x 524,288 fp32
    float* b2  = Gs + 16 * (size_t)NS;
    float* Qb  = b2 + (size_t)HH * NS;
    float* Kb  = Qb + 65536;
    float* Sf  = Gs + 12 * (size_t)NS;         // alias G3 fp32 block (consumed before gemm3)

    const size_t need_bytes =
        (size_t)(4194304 + 4194304 + 32768 + 2097152 + 2097152 + 2097152) * 2 +
        (size_t)(16 * (size_t)NS + HH * NS + 65536 + 65536) * 4;
    if (ws_size < need_bytes) return;

    qk_kernel<<<NN * HH * DE / 256, 256, 0, stream>>>(psi_emb, W_q, W_k, Qb, Kb);
    adj_kernel<<<NN, 256, 0, stream>>>(psi_emb, psi, attn_alpha, Qb, Kb, At);
    xt_cast<<<dim3(NN / 64, BB), 256, 0, stream>>>(x, xt);
    wtt_cast<<<16, 256, 0, stream>>>(F_w, wtt);
    g_mfma<<<dim3(4, NN / 64, BB / 2), 256, 0, stream>>>(xt, wtt, Gs, g3t);

    const dim3 gg(BD / 64, NN / 64, HH);
    // b2 = G2 + 2*A@G3          (G2 slabs at Gs + 8*NS, h-stride NS)
    gemm_mf<<<gg, 256, 0, stream>>>(At, g3t, Gs + 8 * (size_t)NS, Gs + 8 * (size_t)NS,
                                    b2, b2t, 2.f, 1.f, 0.f, 1, 1);
    // b1 = G1 + 2*A@b2 - G3     (fp32 b1 dead: only bf16 b1t consumed)
    gemm_mf<<<gg, 256, 0, stream>>>(At, b2t, Gs + 4 * (size_t)NS, Gs + 12 * (size_t)NS,
                                    b2 /*unused O*/, b1t, 2.f, 1.f, -1.f, 0, 1);
    // Sf = G0 + A@b1 - b2       (Sf aliases G3 fp32 block, already consumed)
    gemm_mf<<<gg, 256, 0, stream>>>(At, b1t, Gs, b2,
                                    Sf, b1t /*unused Ot*/, 1.f, 1.f, -1.f, 1, 0);

    out_kernel<<<BB * NN / 256, 256, 0, stream>>>(psi_emb, f_b, head_mix, Sf, out);
}

// Round 6
// 186.808 us; speedup vs baseline: 1.1926x; 1.1926x over previous
//
#include <hip/hip_runtime.h>
#include <cstdint>

#define NN 1024
#define BB 32
#define LL 128
#define DE 16
#define HH 4
#define K1 4
#define BD 512
#define NS 524288   // NN*BD, floats per head slab

using bf16x8 = __attribute__((ext_vector_type(8))) short;
using f32x4  = __attribute__((ext_vector_type(4))) float;

__device__ inline unsigned short f2bf(float f) {
    unsigned u = __builtin_bit_cast(unsigned, f);
    u += 0x7FFFu + ((u >> 16) & 1u);          // round-to-nearest-even
    return (unsigned short)(u >> 16);
}
__device__ inline float bf2f(unsigned short u) {
    return __builtin_bit_cast(float, (unsigned)u << 16);
}

// ---------------------------------------------------------------- Q/K projections
__global__ __launch_bounds__(256) void qk_kernel(
    const float* __restrict__ psi_emb, const float* __restrict__ W_q,
    const float* __restrict__ W_k, float* __restrict__ Qbuf, float* __restrict__ Kbuf)
{
    const int idx = blockIdx.x * 256 + threadIdx.x;   // N*H*DE = 65536
    const int n = idx >> 6;
    const int hm = idx & 63;
    const float* e = psi_emb + n * DE;
    float q = 0.f, k = 0.f;
#pragma unroll
    for (int d = 0; d < DE; d++) {
        const float ev = e[d];
        q += ev * W_q[d * 64 + hm];
        k += ev * W_k[d * 64 + hm];
    }
    Qbuf[idx] = q;
    Kbuf[idx] = k;
}

// ---------------------------------------------------------------- adjacency pass 1
// R5 post-mortem: per-lane row gathers (lane stride 256 B) are TA/L1
// lookup-bound (~64 lines per load instr) -> VALUBusy 8%. Fix: stage tiles
// coalesced into LDS; all hot-loop reads are LDS broadcasts (free) or
// 17-padded own-row reads (2-way, free). Writes bf16 numerators in the
// tiled At layout + deterministic per-block partial row sums.
__global__ __launch_bounds__(256) void logits_pass(
    const float* __restrict__ psi_emb, const float* __restrict__ psi_p,
    const float* __restrict__ Qbuf, const float* __restrict__ Kbuf,
    short* __restrict__ bnt, short* __restrict__ ant, float* __restrict__ partials)
{
    const int jb = blockIdx.x, ib = blockIdx.y;
    const int i0 = ib * 64, j0 = jb * 64;
    __shared__ float ejs[64][17];
    __shared__ float eis[64][17];
    __shared__ float kjs[64][64];
    __shared__ float qis[4][64][17];
    __shared__ float part[4][5][64];
    const int tid = threadIdx.x;

    {   // psi_emb rows (i tile + j tile): 1024 dwords each, one float4/thread
        const int row = tid >> 2, dq = (tid & 3) * 4;
        const float4 vj = *(const float4*)(psi_emb + (j0 + row) * DE + dq);
        ejs[row][dq] = vj.x; ejs[row][dq + 1] = vj.y;
        ejs[row][dq + 2] = vj.z; ejs[row][dq + 3] = vj.w;
        const float4 vi = *(const float4*)(psi_emb + (i0 + row) * DE + dq);
        eis[row][dq] = vi.x; eis[row][dq + 1] = vi.y;
        eis[row][dq + 2] = vi.z; eis[row][dq + 3] = vi.w;
    }
#pragma unroll
    for (int rep = 0; rep < 4; rep++) {   // K tile: 4096 dwords
        const int idx = rep * 256 + tid;
        const int row = idx >> 4, c4 = (idx & 15) * 4;
        *(float4*)&kjs[row][c4] = *(const float4*)(Kbuf + (size_t)(j0 + row) * 64 + c4);
    }
#pragma unroll
    for (int rep = 0; rep < 4; rep++) {   // Q tile: 4096 dwords, scatter to padded
        const int idx = rep * 256 + tid;
        const int row = idx >> 4, c4 = (idx & 15) * 4;
        const int h = c4 >> 4, m0 = c4 & 15;
        const float4 v = *(const float4*)(Qbuf + (size_t)(i0 + row) * 64 + c4);
        qis[h][row][m0] = v.x; qis[h][row][m0 + 1] = v.y;
        qis[h][row][m0 + 2] = v.z; qis[h][row][m0 + 3] = v.w;
    }
    __syncthreads();

    const int i = tid & 63, jg = tid >> 6;
    const float psi = psi_p[0];
    float er[DE];
#pragma unroll
    for (int d = 0; d < DE; d++) er[d] = eis[i][d];

    float sb = 0.f, sa[HH] = {0.f, 0.f, 0.f, 0.f};
#pragma unroll
    for (int g = 0; g < 2; g++) {          // base numerators, 8 j's per group
        unsigned short bw[8];
#pragma unroll
        for (int r = 0; r < 8; r++) {
            const int j = jg * 16 + g * 8 + r;
            float d2 = 0.f;
#pragma unroll
            for (int d = 0; d < DE; d++) { const float t = er[d] - ejs[j][d]; d2 += t * t; }
            const float bn = __expf(__expf(-psi * d2));
            sb += bn;
            bw[r] = f2bf(bn);
        }
        uint4 pk;
        pk.x = bw[0] | ((unsigned)bw[1] << 16);
        pk.y = bw[2] | ((unsigned)bw[3] << 16);
        pk.z = bw[4] | ((unsigned)bw[5] << 16);
        pk.w = bw[6] | ((unsigned)bw[7] << 16);
        const size_t toff = (size_t)((j0 + jg * 16 + g * 8) >> 3) * 8192 + (size_t)(i0 + i) * 8;
        *(uint4*)(bnt + toff) = pk;
    }
#pragma unroll
    for (int h = 0; h < HH; h++) {         // attention numerators
        float qr[DE];
#pragma unroll
        for (int m = 0; m < DE; m++) qr[m] = qis[h][i][m];
#pragma unroll
        for (int g = 0; g < 2; g++) {
            unsigned short aw[8];
#pragma unroll
            for (int r = 0; r < 8; r++) {
                const int j = jg * 16 + g * 8 + r;
                float dot = 0.f;
#pragma unroll
                for (int m = 0; m < DE; m++) dot += qr[m] * kjs[j][h * DE + m];
                const float an = __expf(dot * 0.25f);
                sa[h] += an;
                aw[r] = f2bf(an);
            }
            uint4 pk;
            pk.x = aw[0] | ((unsigned)aw[1] << 16);
            pk.y = aw[2] | ((unsigned)aw[3] << 16);
            pk.z = aw[4] | ((unsigned)aw[5] << 16);
            pk.w = aw[6] | ((unsigned)aw[7] << 16);
            const size_t toff = (size_t)((j0 + jg * 16 + g * 8) >> 3) * 8192 + (size_t)(i0 + i) * 8;
            *(uint4*)(ant + (size_t)h * 1048576 + toff) = pk;
        }
    }
    // per-block partial row sums (deterministic)
    part[jg][0][i] = sb;
#pragma unroll
    for (int h = 0; h < HH; h++) part[jg][1 + h][i] = sa[h];
    __syncthreads();
    if (tid < 64) {
#pragma unroll
        for (int s = 0; s < 5; s++) {
            const float v = part[0][s][tid] + part[1][s][tid] + part[2][s][tid] + part[3][s][tid];
            partials[(size_t)jb * 5120 + (size_t)s * 1024 + i0 + tid] = v;
        }
    }
}

// ---------------------------------------------------------------- adjacency pass 2
// Combine partial row sums, normalize+blend numerators -> At (bf16, tiled).
__global__ __launch_bounds__(256) void blend_kernel(
    const short* __restrict__ bnt, const short* __restrict__ ant,
    const float* __restrict__ partials, const float* __restrict__ alpha_p,
    short* __restrict__ At)
{
    const int jb = blockIdx.x, ib = blockIdx.y;
    const int i0 = ib * 64, j0 = jb * 64;
    __shared__ float sums_l[5][64];
    const int tid = threadIdx.x;
    const int lane = tid & 63, w = tid >> 6;
    {
        float acc = 0.f;
#pragma unroll
        for (int jb2 = 0; jb2 < 16; jb2++)
            acc += partials[(size_t)jb2 * 5120 + (size_t)w * 1024 + i0 + lane];
        sums_l[w][lane] = acc;
        if (w == 0) {
            float a4 = 0.f;
#pragma unroll
            for (int jb2 = 0; jb2 < 16; jb2++)
                a4 += partials[(size_t)jb2 * 5120 + 4 * 1024 + i0 + lane];
            sums_l[4][lane] = a4;
        }
    }
    __syncthreads();
    const int i = lane, jg = w;
    const float alpha = 1.f / (1.f + __expf(-alpha_p[0]));
    const float ibs = alpha / sums_l[0][i];
    float ias[HH];
#pragma unroll
    for (int h = 0; h < HH; h++) ias[h] = (1.f - alpha) / sums_l[1 + h][i];

#pragma unroll
    for (int g = 0; g < 2; g++) {
        const size_t toff = (size_t)((j0 + jg * 16 + g * 8) >> 3) * 8192 + (size_t)(i0 + i) * 8;
        const uint4 bp = *(const uint4*)(bnt + toff);
        float bnv[8];
        bnv[0] = bf2f(bp.x & 0xFFFF); bnv[1] = bf2f(bp.x >> 16);
        bnv[2] = bf2f(bp.y & 0xFFFF); bnv[3] = bf2f(bp.y >> 16);
        bnv[4] = bf2f(bp.z & 0xFFFF); bnv[5] = bf2f(bp.z >> 16);
        bnv[6] = bf2f(bp.w & 0xFFFF); bnv[7] = bf2f(bp.w >> 16);
#pragma unroll
        for (int h = 0; h < HH; h++) {
            const uint4 ap = *(const uint4*)(ant + (size_t)h * 1048576 + toff);
            float av[8];
            av[0] = bf2f(ap.x & 0xFFFF); av[1] = bf2f(ap.x >> 16);
            av[2] = bf2f(ap.y & 0xFFFF); av[3] = bf2f(ap.y >> 16);
            av[4] = bf2f(ap.z & 0xFFFF); av[5] = bf2f(ap.z >> 16);
            av[6] = bf2f(ap.w & 0xFFFF); av[7] = bf2f(ap.w >> 16);
            unsigned short ow[8];
#pragma unroll
            for (int r = 0; r < 8; r++) ow[r] = f2bf(ibs * bnv[r] + ias[h] * av[r]);
            uint4 pk;
            pk.x = ow[0] | ((unsigned)ow[1] << 16);
            pk.y = ow[2] | ((unsigned)ow[3] << 16);
            pk.z = ow[4] | ((unsigned)ow[5] << 16);
            pk.w = ow[6] | ((unsigned)ow[7] << 16);
            *(uint4*)(At + (size_t)h * 1048576 + toff) = pk;
        }
    }
}

// ---------------------------------------------------------------- x -> xt (bf16, A-fragment-tiled per b)
__global__ __launch_bounds__(256) void xt_cast(
    const float* __restrict__ x, short* __restrict__ xt)
{
    const int m0 = blockIdx.x * 64;
    const int b  = blockIdx.y;
    __shared__ float xs[64][128];
    const int tid = threadIdx.x;
    for (int i = tid; i < 2048; i += 256) {
        const int row = i >> 5, lq = i & 31;
        *(float4*)&xs[row][lq * 4] =
            *(const float4*)(x + ((size_t)(b * NN + m0 + row)) * LL + lq * 4);
    }
    __syncthreads();
    for (int j = tid; j < 1024; j += 256) {
        const int m = j & 63, lc = j >> 6;
        const float* s = &xs[m][lc * 8];
        uint4 pk;
        pk.x = f2bf(s[0]) | ((unsigned)f2bf(s[1]) << 16);
        pk.y = f2bf(s[2]) | ((unsigned)f2bf(s[3]) << 16);
        pk.z = f2bf(s[4]) | ((unsigned)f2bf(s[5]) << 16);
        pk.w = f2bf(s[6]) | ((unsigned)f2bf(s[7]) << 16);
        *(uint4*)(xt + (size_t)b * 131072 + (size_t)lc * 8192 + (size_t)(m0 + m) * 8) = pk;
    }
}

// ---------------------------------------------------------------- F_w -> wtt (bf16, B-fragment-tiled)
__global__ __launch_bounds__(256) void wtt_cast(
    const float* __restrict__ F_w, short* __restrict__ wtt)
{
    const int j = blockIdx.x * 256 + threadIdx.x;     // 16*256
    const int lc = j >> 8, c = j & 255;
    const int h = c >> 6, k = (c >> 4) & 3, d = c & 15;
    const float* s = F_w + (size_t)((h * DE + d) * K1 + k) * LL + lc * 8;
    uint4 pk;
    pk.x = f2bf(s[0]) | ((unsigned)f2bf(s[1]) << 16);
    pk.y = f2bf(s[2]) | ((unsigned)f2bf(s[3]) << 16);
    pk.z = f2bf(s[4]) | ((unsigned)f2bf(s[5]) << 16);
    pk.w = f2bf(s[6]) | ((unsigned)f2bf(s[7]) << 16);
    *(uint4*)(wtt + (size_t)lc * 2048 + (size_t)c * 8) = pk;
}

// ---------------------------------------------------------------- G stage (MFMA, K=128, registers only)
__global__ __launch_bounds__(256) void g_mfma(
    const short* __restrict__ xt, const short* __restrict__ wtt,
    float* __restrict__ Gs, short* __restrict__ g3t)
{
    const int cb = blockIdx.x;           // 0..3  (64 cols)
    const int m0 = blockIdx.y * 64;      // 0..15
    const int bp = blockIdx.z;           // 0..15 (b pair)
    const int tid = threadIdx.x;
    const int wave = tid >> 6, lane = tid & 63;
    const int b  = bp * 2 + (wave >> 1);
    const int wc = wave & 1;
    const int q = lane >> 4, m16 = lane & 15;
    const short* xb = xt + (size_t)b * 131072;

    f32x4 acc[4][2];
#pragma unroll
    for (int mi = 0; mi < 4; mi++)
#pragma unroll
        for (int ni = 0; ni < 2; ni++) acc[mi][ni] = (f32x4){0.f, 0.f, 0.f, 0.f};

#pragma unroll
    for (int ks = 0; ks < 4; ks++) {
        const int kc = ks * 4 + q;
        bf16x8 a[4], bb[2];
#pragma unroll
        for (int mi = 0; mi < 4; mi++)
            a[mi] = *(const bf16x8*)(xb + (size_t)kc * 8192 + (size_t)(m0 + mi * 16 + m16) * 8);
#pragma unroll
        for (int ni = 0; ni < 2; ni++)
            bb[ni] = *(const bf16x8*)(wtt + (size_t)kc * 2048 +
                                      (size_t)(cb * 64 + wc * 32 + ni * 16 + m16) * 8);
#pragma unroll
        for (int mi = 0; mi < 4; mi++)
#pragma unroll
            for (int ni = 0; ni < 2; ni++)
                acc[mi][ni] = __builtin_amdgcn_mfma_f32_16x16x32_bf16(a[mi], bb[ni], acc[mi][ni], 0, 0, 0);
    }

#pragma unroll
    for (int ni = 0; ni < 2; ni++) {
        const int cc = cb * 64 + wc * 32 + ni * 16 + m16;
        const int kk = (cc >> 4) & 3, hh = cc >> 6;
        const int slab = kk * 4 + hh;
        const int col512 = b * 16 + (cc & 15);
        float* gdst = Gs + (size_t)slab * NS;
#pragma unroll
        for (int mi = 0; mi < 4; mi++) {
            const int row0 = m0 + mi * 16 + q * 4;
#pragma unroll
            for (int r = 0; r < 4; r++)
                gdst[(size_t)(row0 + r) * BD + col512] = acc[mi][ni][r];
            if (kk == 3) {
                ushort4 pk;
                pk.x = f2bf(acc[mi][ni][0]); pk.y = f2bf(acc[mi][ni][1]);
                pk.z = f2bf(acc[mi][ni][2]); pk.w = f2bf(acc[mi][ni][3]);
                *(ushort4*)(g3t + (size_t)hh * 524288 +
                            ((size_t)(row0 >> 3) * 512 + col512) * 8 + (row0 & 7)) = pk;
            }
        }
    }
}

// ---------------------------------------------------------------- Clenshaw GEMM (MFMA)
__global__ __launch_bounds__(256) void gemm_mf(
    const short* __restrict__ At, const short* __restrict__ Bt,
    const float* __restrict__ P, const float* __restrict__ Q,
    float* __restrict__ O, short* __restrict__ Ot,
    float scale, float pc, float qc, int writeO, int writeOt)
{
    const int h = blockIdx.z;
    const short* Ah = At + (size_t)h * 1048576;
    const short* Bh = Bt + (size_t)h * 524288;
    const float* Ph = P + (size_t)h * NS;
    const float* Qh = Q + (size_t)h * NS;
    float* Oh = O + (size_t)h * NS;
    short* Oth = Ot + (size_t)h * 524288;

    const int c0 = blockIdx.x * 64;
    const int r0 = blockIdx.y * 64;
    const int tid = threadIdx.x;
    const int wave = tid >> 6, lane = tid & 63;
    const int q = lane >> 4, m16 = lane & 15;
    const int wr = wave >> 1, wc = wave & 1;

    __shared__ __align__(16) short As[2][2048];
    __shared__ __align__(16) short Bs[2][2048];

    {
        uint4 ra = *(const uint4*)(Ah + ((size_t)wave * 1024 + r0 + lane) * 8);
        uint4 rb = *(const uint4*)(Bh + ((size_t)wave * 512 + c0 + lane) * 8);
        *(uint4*)&As[0][wave * 512 + lane * 8] = ra;
        *(uint4*)&Bs[0][wave * 512 + lane * 8] = rb;
    }
    __syncthreads();

    f32x4 acc[2][2];
#pragma unroll
    for (int mi = 0; mi < 2; mi++)
#pragma unroll
        for (int ni = 0; ni < 2; ni++) acc[mi][ni] = (f32x4){0.f, 0.f, 0.f, 0.f};

    int buf = 0;
    for (int k0 = 32; k0 <= 1024; k0 += 32) {
        uint4 na, nb;
        const bool more = (k0 < 1024);
        if (more) {
            na = *(const uint4*)(Ah + (((size_t)(k0 >> 3) + wave) * 1024 + r0 + lane) * 8);
            nb = *(const uint4*)(Bh + (((size_t)(k0 >> 3) + wave) * 512 + c0 + lane) * 8);
        }
        bf16x8 af0 = *(const bf16x8*)&As[buf][q * 512 + (wr * 32 + m16) * 8];
        bf16x8 af1 = *(const bf16x8*)&As[buf][q * 512 + (wr * 32 + 16 + m16) * 8];
        bf16x8 bf0 = *(const bf16x8*)&Bs[buf][q * 512 + (wc * 32 + m16) * 8];
        bf16x8 bf1 = *(const bf16x8*)&Bs[buf][q * 512 + (wc * 32 + 16 + m16) * 8];
        acc[0][0] = __builtin_amdgcn_mfma_f32_16x16x32_bf16(af0, bf0, acc[0][0], 0, 0, 0);
        acc[0][1] = __builtin_amdgcn_mfma_f32_16x16x32_bf16(af0, bf1, acc[0][1], 0, 0, 0);
        acc[1][0] = __builtin_amdgcn_mfma_f32_16x16x32_bf16(af1, bf0, acc[1][0], 0, 0, 0);
        acc[1][1] = __builtin_amdgcn_mfma_f32_16x16x32_bf16(af1, bf1, acc[1][1], 0, 0, 0);
        if (more) {
            const int nx = buf ^ 1;
            *(uint4*)&As[nx][wave * 512 + lane * 8] = na;
            *(uint4*)&Bs[nx][wave * 512 + lane * 8] = nb;
            __syncthreads();
            buf = nx;
        }
    }

#pragma unroll
    for (int mi = 0; mi < 2; mi++) {
        const int row0 = r0 + wr * 32 + mi * 16 + q * 4;
#pragma unroll
        for (int ni = 0; ni < 2; ni++) {
            const int cc = c0 + wc * 32 + ni * 16 + m16;
            float v[4];
#pragma unroll
            for (int r = 0; r < 4; r++) {
                const size_t off = (size_t)(row0 + r) * BD + cc;
                float t = scale * acc[mi][ni][r] + pc * Ph[off];
                if (qc != 0.f) t += qc * Qh[off];
                v[r] = t;
                if (writeO) Oh[off] = t;
            }
            if (writeOt) {
                ushort4 pk;
                pk.x = f2bf(v[0]); pk.y = f2bf(v[1]); pk.z = f2bf(v[2]); pk.w = f2bf(v[3]);
                *(ushort4*)(Oth + ((size_t)(row0 >> 3) * 512 + cc) * 8 + (row0 & 7)) = pk;
            }
        }
    }
}

// ---------------------------------------------------------------- final contraction
__global__ __launch_bounds__(256) void out_kernel(
    const float* __restrict__ psi_emb, const float* __restrict__ f_b,
    const float* __restrict__ head_mix, const float* __restrict__ S,
    float* __restrict__ out)
{
    const int id = blockIdx.x * 256 + threadIdx.x;  // id = b*N + n
    const int n = id & (NN - 1);
    const int b = id >> 10;
    const float hm0 = head_mix[0], hm1 = head_mix[1], hm2 = head_mix[2], hm3 = head_mix[3];
    const float mx = fmaxf(fmaxf(hm0, hm1), fmaxf(hm2, hm3));
    const float w0 = expf(hm0 - mx), w1 = expf(hm1 - mx), w2 = expf(hm2 - mx), w3 = expf(hm3 - mx);
    const float isum = 1.f / (w0 + w1 + w2 + w3);
    const float mw[4] = {w0 * isum, w1 * isum, w2 * isum, w3 * isum};
    float e[DE];
#pragma unroll
    for (int d = 0; d < DE; d++) e[d] = psi_emb[n * DE + d];
    float total = 0.f;
#pragma unroll
    for (int h = 0; h < HH; h++) {
        const float* sp = S + ((size_t)h * NN + n) * BD + b * DE;
        const float* fb = f_b + h * DE;
        float acc = 0.f;
#pragma unroll
        for (int d = 0; d < DE; d++) acc += e[d] * (sp[d] + fb[d]);
        total += mw[h] * acc;
    }
    out[id] = total;
}

extern "C" void kernel_launch(void* const* d_in, const int* in_sizes, int n_in,
                              void* d_out, int out_size, void* d_ws, size_t ws_size,
                              hipStream_t stream)
{
    const float* x          = (const float*)d_in[0];
    const float* psi_emb    = (const float*)d_in[1];
    const float* psi        = (const float*)d_in[2];
    const float* W_q        = (const float*)d_in[3];
    const float* W_k        = (const float*)d_in[4];
    const float* attn_alpha = (const float*)d_in[5];
    const float* F_w        = (const float*)d_in[6];
    const float* f_b        = (const float*)d_in[7];
    const float* head_mix   = (const float*)d_in[8];
    float* out = (float*)d_out;

    short* At  = (short*)d_ws;                 // 4,194,304 bf16 (tiled, per-h 1,048,576)
    short* xt  = At + 4194304;                 // 4,194,304
    short* wtt = xt + 4194304;                 // 32,768
    short* g3t = wtt + 32768;                  // 2,097,152 (per-h 524,288)
    short* b2t = g3t + 2097152;                // 2,097,152
    short* b1t = b2t + 2097152;                // 2,097,152
    short* bnt = b1t + 2097152;                // 1,048,576 (base numerators)
    short* ant = bnt + 1048576;                // 4,194,304 (attn numerators)
    float* Gs  = (float*)(ant + 4194304);      // 16 slabs (k*4+h) x 524,288 fp32
    float* b2  = Gs + 16 * (size_t)NS;
    float* Qb  = b2 + (size_t)HH * NS;
    float* Kb  = Qb + 65536;
    float* partials = Kb + 65536;              // 16 * 5 * 1024 = 81,920 fp32
    float* Sf  = Gs + 12 * (size_t)NS;         // alias G3 fp32 block (consumed before gemm3)

    const size_t need_bytes =
        (size_t)(4194304 + 4194304 + 32768 + 2097152 + 2097152 + 2097152 + 1048576 + 4194304) * 2 +
        (size_t)(16 * (size_t)NS + HH * NS + 65536 + 65536 + 81920) * 4;
    if (ws_size < need_bytes) return;

    qk_kernel<<<NN * HH * DE / 256, 256, 0, stream>>>(psi_emb, W_q, W_k, Qb, Kb);
    logits_pass<<<dim3(16, 16), 256, 0, stream>>>(psi_emb, psi, Qb, Kb, bnt, ant, partials);
    blend_kernel<<<dim3(16, 16), 256, 0, stream>>>(bnt, ant, partials, attn_alpha, At);
    xt_cast<<<dim3(NN / 64, BB), 256, 0, stream>>>(x, xt);
    wtt_cast<<<16, 256, 0, stream>>>(F_w, wtt);
    g_mfma<<<dim3(4, NN / 64, BB / 2), 256, 0, stream>>>(xt, wtt, Gs, g3t);

    const dim3 gg(BD / 64, NN / 64, HH);
    // b2 = G2 + 2*A@G3          (G2 slabs at Gs + 8*NS, h-stride NS)
    gemm_mf<<<gg, 256, 0, stream>>>(At, g3t, Gs + 8 * (size_t)NS, Gs + 8 * (size_t)NS,
                                    b2, b2t, 2.f, 1.f, 0.f, 1, 1);
    // b1 = G1 + 2*A@b2 - G3     (fp32 b1 dead: only bf16 b1t consumed)
    gemm_mf<<<gg, 256, 0, stream>>>(At, b2t, Gs + 4 * (size_t)NS, Gs + 12 * (size_t)NS,
                                    b2 /*unused O*/, b1t, 2.f, 1.f, -1.f, 0, 1);
    // Sf = G0 + A@b1 - b2       (Sf aliases G3 fp32 block, already consumed)
    gemm_mf<<<gg, 256, 0, stream>>>(At, b1t, Gs, b2,
                                    Sf, b1t /*unused Ot*/, 1.f, 1.f, -1.f, 1, 0);

    out_kernel<<<BB * NN / 256, 256, 0, stream>>>(psi_emb, f_b, head_mix, Sf, out);
}

// Round 7
// 173.089 us; speedup vs baseline: 1.2871x; 1.0793x over previous
//
#include <hip/hip_runtime.h>
#include <cstdint>

#define NN 1024
#define BB 32
#define LL 128
#define DE 16
#define HH 4
#define K1 4
#define BD 512
#define NS 524288   // NN*BD, floats per head slab

using bf16x8 = __attribute__((ext_vector_type(8))) short;
using f32x4  = __attribute__((ext_vector_type(4))) float;

__device__ inline unsigned short f2bf(float f) {
    unsigned u = __builtin_bit_cast(unsigned, f);
    u += 0x7FFFu + ((u >> 16) & 1u);          // round-to-nearest-even
    return (unsigned short)(u >> 16);
}
__device__ inline float bf2f(unsigned short u) {
    return __builtin_bit_cast(float, (unsigned)u << 16);
}

struct LogitsSmem {
    float ejs[64][17];
    float eis[64][17];
    float kjs[64][64];
    float qis[4][64][17];
    float part[4][5][64];
    float wq[1024];
    float wk[1024];
};
struct XtSmem { float xs[64][128]; };

// ================================================================ PHASE 1
// Fused: logits (256 blocks, with inline per-tile Q/K projection),
//        xt_cast (512 blocks), wtt_cast (16 blocks). R6 post-mortem: chain is
//        dispatch-count-bound (~10us/launch); fusing independent producers.
__global__ __launch_bounds__(256) void phase1(
    const float* __restrict__ psi_emb, const float* __restrict__ psi_p,
    const float* __restrict__ W_q, const float* __restrict__ W_k,
    const float* __restrict__ x, const float* __restrict__ F_w,
    short* __restrict__ bnt, short* __restrict__ ant, float* __restrict__ partials,
    short* __restrict__ xt, short* __restrict__ wtt)
{
    __shared__ __align__(16) char smem_raw[sizeof(LogitsSmem)];
    const int bid = blockIdx.x;
    const int tid = threadIdx.x;

    if (bid < 256) {
        // ---------------- logits role
        LogitsSmem& S = *(LogitsSmem*)smem_raw;
        const int jb = bid & 15, ib = bid >> 4;
        const int i0 = ib * 64, j0 = jb * 64;
        {   // stage psi_emb i-rows and j-rows
            const int row = tid >> 2, dq = (tid & 3) * 4;
            const float4 vj = *(const float4*)(psi_emb + (j0 + row) * DE + dq);
            S.ejs[row][dq] = vj.x; S.ejs[row][dq + 1] = vj.y;
            S.ejs[row][dq + 2] = vj.z; S.ejs[row][dq + 3] = vj.w;
            const float4 vi = *(const float4*)(psi_emb + (i0 + row) * DE + dq);
            S.eis[row][dq] = vi.x; S.eis[row][dq + 1] = vi.y;
            S.eis[row][dq + 2] = vi.z; S.eis[row][dq + 3] = vi.w;
            // stage W_q / W_k (1024 floats each)
            *(float4*)&S.wq[tid * 4] = *(const float4*)(W_q + tid * 4);
            *(float4*)&S.wk[tid * 4] = *(const float4*)(W_k + tid * 4);
        }
        __syncthreads();
        // inline Q (i-tile) and K (j-tile) projections: 4096 elems each
#pragma unroll
        for (int rep = 0; rep < 16; rep++) {
            const int idx = rep * 256 + tid;
            const int row = idx >> 6, hm = idx & 63;
            float qv = 0.f, kv = 0.f;
#pragma unroll
            for (int d = 0; d < DE; d++) {
                qv += S.eis[row][d] * S.wq[d * 64 + hm];
                kv += S.ejs[row][d] * S.wk[d * 64 + hm];
            }
            S.qis[hm >> 4][row][hm & 15] = qv;
            S.kjs[row][hm] = kv;
        }
        __syncthreads();

        const int i = tid & 63, jg = tid >> 6;
        const float psi = psi_p[0];
        float er[DE];
#pragma unroll
        for (int d = 0; d < DE; d++) er[d] = S.eis[i][d];

        float sb = 0.f, sa[HH] = {0.f, 0.f, 0.f, 0.f};
#pragma unroll
        for (int g = 0; g < 2; g++) {
            unsigned short bw[8];
#pragma unroll
            for (int r = 0; r < 8; r++) {
                const int j = jg * 16 + g * 8 + r;
                float d2 = 0.f;
#pragma unroll
                for (int d = 0; d < DE; d++) { const float t = er[d] - S.ejs[j][d]; d2 += t * t; }
                const float bn = __expf(__expf(-psi * d2));
                sb += bn;
                bw[r] = f2bf(bn);
            }
            uint4 pk;
            pk.x = bw[0] | ((unsigned)bw[1] << 16);
            pk.y = bw[2] | ((unsigned)bw[3] << 16);
            pk.z = bw[4] | ((unsigned)bw[5] << 16);
            pk.w = bw[6] | ((unsigned)bw[7] << 16);
            const size_t toff = (size_t)((j0 + jg * 16 + g * 8) >> 3) * 8192 + (size_t)(i0 + i) * 8;
            *(uint4*)(bnt + toff) = pk;
        }
#pragma unroll
        for (int h = 0; h < HH; h++) {
            float qr[DE];
#pragma unroll
            for (int m = 0; m < DE; m++) qr[m] = S.qis[h][i][m];
#pragma unroll
            for (int g = 0; g < 2; g++) {
                unsigned short aw[8];
#pragma unroll
                for (int r = 0; r < 8; r++) {
                    const int j = jg * 16 + g * 8 + r;
                    float dot = 0.f;
#pragma unroll
                    for (int m = 0; m < DE; m++) dot += qr[m] * S.kjs[j][h * DE + m];
                    const float an = __expf(dot * 0.25f);
                    sa[h] += an;
                    aw[r] = f2bf(an);
                }
                uint4 pk;
                pk.x = aw[0] | ((unsigned)aw[1] << 16);
                pk.y = aw[2] | ((unsigned)aw[3] << 16);
                pk.z = aw[4] | ((unsigned)aw[5] << 16);
                pk.w = aw[6] | ((unsigned)aw[7] << 16);
                const size_t toff = (size_t)((j0 + jg * 16 + g * 8) >> 3) * 8192 + (size_t)(i0 + i) * 8;
                *(uint4*)(ant + (size_t)h * 1048576 + toff) = pk;
            }
        }
        S.part[jg][0][i] = sb;
#pragma unroll
        for (int h = 0; h < HH; h++) S.part[jg][1 + h][i] = sa[h];
        __syncthreads();
        if (tid < 64) {
#pragma unroll
            for (int s = 0; s < 5; s++) {
                const float v = S.part[0][s][tid] + S.part[1][s][tid] +
                                S.part[2][s][tid] + S.part[3][s][tid];
                partials[(size_t)jb * 5120 + (size_t)s * 1024 + i0 + tid] = v;
            }
        }
    } else if (bid < 768) {
        // ---------------- xt_cast role
        XtSmem& X = *(XtSmem*)smem_raw;
        const int idx = bid - 256;
        const int m0 = (idx & 15) * 64;
        const int b  = idx >> 4;
        for (int i = tid; i < 2048; i += 256) {
            const int row = i >> 5, lq = i & 31;
            *(float4*)&X.xs[row][lq * 4] =
                *(const float4*)(x + ((size_t)(b * NN + m0 + row)) * LL + lq * 4);
        }
        __syncthreads();
        for (int j = tid; j < 1024; j += 256) {
            const int m = j & 63, lc = j >> 6;
            const float* s = &X.xs[m][lc * 8];
            uint4 pk;
            pk.x = f2bf(s[0]) | ((unsigned)f2bf(s[1]) << 16);
            pk.y = f2bf(s[2]) | ((unsigned)f2bf(s[3]) << 16);
            pk.z = f2bf(s[4]) | ((unsigned)f2bf(s[5]) << 16);
            pk.w = f2bf(s[6]) | ((unsigned)f2bf(s[7]) << 16);
            *(uint4*)(xt + (size_t)b * 131072 + (size_t)lc * 8192 + (size_t)(m0 + m) * 8) = pk;
        }
    } else {
        // ---------------- wtt_cast role (16 blocks)
        const int j = (bid - 768) * 256 + tid;
        const int lc = j >> 8, c = j & 255;
        const int h = c >> 6, k = (c >> 4) & 3, d = c & 15;
        const float* s = F_w + (size_t)((h * DE + d) * K1 + k) * LL + lc * 8;
        uint4 pk;
        pk.x = f2bf(s[0]) | ((unsigned)f2bf(s[1]) << 16);
        pk.y = f2bf(s[2]) | ((unsigned)f2bf(s[3]) << 16);
        pk.z = f2bf(s[4]) | ((unsigned)f2bf(s[5]) << 16);
        pk.w = f2bf(s[6]) | ((unsigned)f2bf(s[7]) << 16);
        *(uint4*)(wtt + (size_t)lc * 2048 + (size_t)c * 8) = pk;
    }
}

// ================================================================ PHASE 2
// Fused: g_mfma (1024 blocks) + blend (256 blocks).
__global__ __launch_bounds__(256) void phase2(
    const short* __restrict__ xt, const short* __restrict__ wtt,
    float* __restrict__ Gs, short* __restrict__ g3t,
    const short* __restrict__ bnt, const short* __restrict__ ant,
    const float* __restrict__ partials, const float* __restrict__ alpha_p,
    short* __restrict__ At)
{
    const int bid = blockIdx.x;
    const int tid = threadIdx.x;
    __shared__ float sums_l[5][64];

    if (bid < 1024) {
        // ---------------- g_mfma role
        const int cb = bid & 3;
        const int m0 = ((bid >> 2) & 15) * 64;
        const int bp = bid >> 6;
        const int wave = tid >> 6, lane = tid & 63;
        const int b  = bp * 2 + (wave >> 1);
        const int wc = wave & 1;
        const int q = lane >> 4, m16 = lane & 15;
        const short* xb = xt + (size_t)b * 131072;

        f32x4 acc[4][2];
#pragma unroll
        for (int mi = 0; mi < 4; mi++)
#pragma unroll
            for (int ni = 0; ni < 2; ni++) acc[mi][ni] = (f32x4){0.f, 0.f, 0.f, 0.f};

#pragma unroll
        for (int ks = 0; ks < 4; ks++) {
            const int kc = ks * 4 + q;
            bf16x8 a[4], bb[2];
#pragma unroll
            for (int mi = 0; mi < 4; mi++)
                a[mi] = *(const bf16x8*)(xb + (size_t)kc * 8192 + (size_t)(m0 + mi * 16 + m16) * 8);
#pragma unroll
            for (int ni = 0; ni < 2; ni++)
                bb[ni] = *(const bf16x8*)(wtt + (size_t)kc * 2048 +
                                          (size_t)(cb * 64 + wc * 32 + ni * 16 + m16) * 8);
#pragma unroll
            for (int mi = 0; mi < 4; mi++)
#pragma unroll
                for (int ni = 0; ni < 2; ni++)
                    acc[mi][ni] = __builtin_amdgcn_mfma_f32_16x16x32_bf16(a[mi], bb[ni], acc[mi][ni], 0, 0, 0);
        }

#pragma unroll
        for (int ni = 0; ni < 2; ni++) {
            const int cc = cb * 64 + wc * 32 + ni * 16 + m16;
            const int kk = (cc >> 4) & 3, hh = cc >> 6;
            const int slab = kk * 4 + hh;
            const int col512 = b * 16 + (cc & 15);
            float* gdst = Gs + (size_t)slab * NS;
#pragma unroll
            for (int mi = 0; mi < 4; mi++) {
                const int row0 = m0 + mi * 16 + q * 4;
#pragma unroll
                for (int r = 0; r < 4; r++)
                    gdst[(size_t)(row0 + r) * BD + col512] = acc[mi][ni][r];
                if (kk == 3) {
                    ushort4 pk;
                    pk.x = f2bf(acc[mi][ni][0]); pk.y = f2bf(acc[mi][ni][1]);
                    pk.z = f2bf(acc[mi][ni][2]); pk.w = f2bf(acc[mi][ni][3]);
                    *(ushort4*)(g3t + (size_t)hh * 524288 +
                                ((size_t)(row0 >> 3) * 512 + col512) * 8 + (row0 & 7)) = pk;
                }
            }
        }
    } else {
        // ---------------- blend role
        const int idx = bid - 1024;
        const int jb = idx & 15, ib = idx >> 4;
        const int i0 = ib * 64, j0 = jb * 64;
        const int lane = tid & 63, w = tid >> 6;
        {
            float acc = 0.f;
#pragma unroll
            for (int jb2 = 0; jb2 < 16; jb2++)
                acc += partials[(size_t)jb2 * 5120 + (size_t)w * 1024 + i0 + lane];
            sums_l[w][lane] = acc;
            if (w == 0) {
                float a4 = 0.f;
#pragma unroll
                for (int jb2 = 0; jb2 < 16; jb2++)
                    a4 += partials[(size_t)jb2 * 5120 + 4 * 1024 + i0 + lane];
                sums_l[4][lane] = a4;
            }
        }
        __syncthreads();
        const int i = lane, jg = w;
        const float alpha = 1.f / (1.f + __expf(-alpha_p[0]));
        const float ibs = alpha / sums_l[0][i];
        float ias[HH];
#pragma unroll
        for (int h = 0; h < HH; h++) ias[h] = (1.f - alpha) / sums_l[1 + h][i];

#pragma unroll
        for (int g = 0; g < 2; g++) {
            const size_t toff = (size_t)((j0 + jg * 16 + g * 8) >> 3) * 8192 + (size_t)(i0 + i) * 8;
            const uint4 bp = *(const uint4*)(bnt + toff);
            float bnv[8];
            bnv[0] = bf2f(bp.x & 0xFFFF); bnv[1] = bf2f(bp.x >> 16);
            bnv[2] = bf2f(bp.y & 0xFFFF); bnv[3] = bf2f(bp.y >> 16);
            bnv[4] = bf2f(bp.z & 0xFFFF); bnv[5] = bf2f(bp.z >> 16);
            bnv[6] = bf2f(bp.w & 0xFFFF); bnv[7] = bf2f(bp.w >> 16);
#pragma unroll
            for (int h = 0; h < HH; h++) {
                const uint4 ap = *(const uint4*)(ant + (size_t)h * 1048576 + toff);
                float av[8];
                av[0] = bf2f(ap.x & 0xFFFF); av[1] = bf2f(ap.x >> 16);
                av[2] = bf2f(ap.y & 0xFFFF); av[3] = bf2f(ap.y >> 16);
                av[4] = bf2f(ap.z & 0xFFFF); av[5] = bf2f(ap.z >> 16);
                av[6] = bf2f(ap.w & 0xFFFF); av[7] = bf2f(ap.w >> 16);
                unsigned short ow[8];
#pragma unroll
                for (int r = 0; r < 8; r++) ow[r] = f2bf(ibs * bnv[r] + ias[h] * av[r]);
                uint4 pk;
                pk.x = ow[0] | ((unsigned)ow[1] << 16);
                pk.y = ow[2] | ((unsigned)ow[3] << 16);
                pk.z = ow[4] | ((unsigned)ow[5] << 16);
                pk.w = ow[6] | ((unsigned)ow[7] << 16);
                *(uint4*)(At + (size_t)h * 1048576 + toff) = pk;
            }
        }
    }
}

// ================================================================ Clenshaw GEMM (MFMA)
__global__ __launch_bounds__(256) void gemm_mf(
    const short* __restrict__ At, const short* __restrict__ Bt,
    const float* __restrict__ P, const float* __restrict__ Q,
    float* __restrict__ O, short* __restrict__ Ot,
    float scale, float pc, float qc, int writeO, int writeOt)
{
    const int h = blockIdx.z;
    const short* Ah = At + (size_t)h * 1048576;
    const short* Bh = Bt + (size_t)h * 524288;
    const float* Ph = P + (size_t)h * NS;
    const float* Qh = Q + (size_t)h * NS;
    float* Oh = O + (size_t)h * NS;
    short* Oth = Ot + (size_t)h * 524288;

    const int c0 = blockIdx.x * 64;
    const int r0 = blockIdx.y * 64;
    const int tid = threadIdx.x;
    const int wave = tid >> 6, lane = tid & 63;
    const int q = lane >> 4, m16 = lane & 15;
    const int wr = wave >> 1, wc = wave & 1;

    __shared__ __align__(16) short As[2][2048];
    __shared__ __align__(16) short Bs[2][2048];

    {
        uint4 ra = *(const uint4*)(Ah + ((size_t)wave * 1024 + r0 + lane) * 8);
        uint4 rb = *(const uint4*)(Bh + ((size_t)wave * 512 + c0 + lane) * 8);
        *(uint4*)&As[0][wave * 512 + lane * 8] = ra;
        *(uint4*)&Bs[0][wave * 512 + lane * 8] = rb;
    }
    __syncthreads();

    f32x4 acc[2][2];
#pragma unroll
    for (int mi = 0; mi < 2; mi++)
#pragma unroll
        for (int ni = 0; ni < 2; ni++) acc[mi][ni] = (f32x4){0.f, 0.f, 0.f, 0.f};

    int buf = 0;
    for (int k0 = 32; k0 <= 1024; k0 += 32) {
        uint4 na, nb;
        const bool more = (k0 < 1024);
        if (more) {
            na = *(const uint4*)(Ah + (((size_t)(k0 >> 3) + wave) * 1024 + r0 + lane) * 8);
            nb = *(const uint4*)(Bh + (((size_t)(k0 >> 3) + wave) * 512 + c0 + lane) * 8);
        }
        bf16x8 af0 = *(const bf16x8*)&As[buf][q * 512 + (wr * 32 + m16) * 8];
        bf16x8 af1 = *(const bf16x8*)&As[buf][q * 512 + (wr * 32 + 16 + m16) * 8];
        bf16x8 bf0 = *(const bf16x8*)&Bs[buf][q * 512 + (wc * 32 + m16) * 8];
        bf16x8 bf1 = *(const bf16x8*)&Bs[buf][q * 512 + (wc * 32 + 16 + m16) * 8];
        acc[0][0] = __builtin_amdgcn_mfma_f32_16x16x32_bf16(af0, bf0, acc[0][0], 0, 0, 0);
        acc[0][1] = __builtin_amdgcn_mfma_f32_16x16x32_bf16(af0, bf1, acc[0][1], 0, 0, 0);
        acc[1][0] = __builtin_amdgcn_mfma_f32_16x16x32_bf16(af1, bf0, acc[1][0], 0, 0, 0);
        acc[1][1] = __builtin_amdgcn_mfma_f32_16x16x32_bf16(af1, bf1, acc[1][1], 0, 0, 0);
        if (more) {
            const int nx = buf ^ 1;
            *(uint4*)&As[nx][wave * 512 + lane * 8] = na;
            *(uint4*)&Bs[nx][wave * 512 + lane * 8] = nb;
            __syncthreads();
            buf = nx;
        }
    }

#pragma unroll
    for (int mi = 0; mi < 2; mi++) {
        const int row0 = r0 + wr * 32 + mi * 16 + q * 4;
#pragma unroll
        for (int ni = 0; ni < 2; ni++) {
            const int cc = c0 + wc * 32 + ni * 16 + m16;
            float v[4];
#pragma unroll
            for (int r = 0; r < 4; r++) {
                const size_t off = (size_t)(row0 + r) * BD + cc;
                float t = scale * acc[mi][ni][r] + pc * Ph[off];
                if (qc != 0.f) t += qc * Qh[off];
                v[r] = t;
                if (writeO) Oh[off] = t;
            }
            if (writeOt) {
                ushort4 pk;
                pk.x = f2bf(v[0]); pk.y = f2bf(v[1]); pk.z = f2bf(v[2]); pk.w = f2bf(v[3]);
                *(ushort4*)(Oth + ((size_t)(row0 >> 3) * 512 + cc) * 8 + (row0 & 7)) = pk;
            }
        }
    }
}

// ================================================================ GEMM3 + fused output contraction
// Sf = G0 + A@b1 - b2 computed in-register; epilogue multiplies (Sf+fb) by
// e[n,d], shfl-reduces over the 16 d-lanes, atomicAdds mw[h]*sum into out.
// Sf is never materialized (saves 16.8 MB write + 8.4 MB read + 1 dispatch).
__global__ __launch_bounds__(256) void gemm3_out(
    const short* __restrict__ At, const short* __restrict__ Bt,
    const float* __restrict__ P, const float* __restrict__ Q,
    const float* __restrict__ psi_emb, const float* __restrict__ f_b,
    const float* __restrict__ head_mix, float* __restrict__ out)
{
    const int h = blockIdx.z;
    const short* Ah = At + (size_t)h * 1048576;
    const short* Bh = Bt + (size_t)h * 524288;
    const float* Ph = P + (size_t)h * NS;
    const float* Qh = Q + (size_t)h * NS;

    const int c0 = blockIdx.x * 64;
    const int r0 = blockIdx.y * 64;
    const int tid = threadIdx.x;
    const int wave = tid >> 6, lane = tid & 63;
    const int q = lane >> 4, m16 = lane & 15;
    const int wr = wave >> 1, wc = wave & 1;

    __shared__ __align__(16) short As[2][2048];
    __shared__ __align__(16) short Bs[2][2048];
    __shared__ float es[64][17];

    {
        uint4 ra = *(const uint4*)(Ah + ((size_t)wave * 1024 + r0 + lane) * 8);
        uint4 rb = *(const uint4*)(Bh + ((size_t)wave * 512 + c0 + lane) * 8);
        *(uint4*)&As[0][wave * 512 + lane * 8] = ra;
        *(uint4*)&Bs[0][wave * 512 + lane * 8] = rb;
        const int row = tid >> 2, dq = (tid & 3) * 4;
        const float4 ev = *(const float4*)(psi_emb + (size_t)(r0 + row) * DE + dq);
        es[row][dq] = ev.x; es[row][dq + 1] = ev.y;
        es[row][dq + 2] = ev.z; es[row][dq + 3] = ev.w;
    }
    __syncthreads();

    f32x4 acc[2][2];
#pragma unroll
    for (int mi = 0; mi < 2; mi++)
#pragma unroll
        for (int ni = 0; ni < 2; ni++) acc[mi][ni] = (f32x4){0.f, 0.f, 0.f, 0.f};

    int buf = 0;
    for (int k0 = 32; k0 <= 1024; k0 += 32) {
        uint4 na, nb;
        const bool more = (k0 < 1024);
        if (more) {
            na = *(const uint4*)(Ah + (((size_t)(k0 >> 3) + wave) * 1024 + r0 + lane) * 8);
            nb = *(const uint4*)(Bh + (((size_t)(k0 >> 3) + wave) * 512 + c0 + lane) * 8);
        }
        bf16x8 af0 = *(const bf16x8*)&As[buf][q * 512 + (wr * 32 + m16) * 8];
        bf16x8 af1 = *(const bf16x8*)&As[buf][q * 512 + (wr * 32 + 16 + m16) * 8];
        bf16x8 bf0 = *(const bf16x8*)&Bs[buf][q * 512 + (wc * 32 + m16) * 8];
        bf16x8 bf1 = *(const bf16x8*)&Bs[buf][q * 512 + (wc * 32 + 16 + m16) * 8];
        acc[0][0] = __builtin_amdgcn_mfma_f32_16x16x32_bf16(af0, bf0, acc[0][0], 0, 0, 0);
        acc[0][1] = __builtin_amdgcn_mfma_f32_16x16x32_bf16(af0, bf1, acc[0][1], 0, 0, 0);
        acc[1][0] = __builtin_amdgcn_mfma_f32_16x16x32_bf16(af1, bf0, acc[1][0], 0, 0, 0);
        acc[1][1] = __builtin_amdgcn_mfma_f32_16x16x32_bf16(af1, bf1, acc[1][1], 0, 0, 0);
        if (more) {
            const int nx = buf ^ 1;
            *(uint4*)&As[nx][wave * 512 + lane * 8] = na;
            *(uint4*)&Bs[nx][wave * 512 + lane * 8] = nb;
            __syncthreads();
            buf = nx;
        }
    }

    // head-mix softmax weight for this h (scalar, broadcast loads)
    const float hm0 = head_mix[0], hm1 = head_mix[1], hm2 = head_mix[2], hm3 = head_mix[3];
    const float mx = fmaxf(fmaxf(hm0, hm1), fmaxf(hm2, hm3));
    const float w0 = expf(hm0 - mx), w1 = expf(hm1 - mx), w2 = expf(hm2 - mx), w3 = expf(hm3 - mx);
    const float isum = 1.f / (w0 + w1 + w2 + w3);
    const float mwh = (h == 0 ? w0 : h == 1 ? w1 : h == 2 ? w2 : w3) * isum;
    const float fb = f_b[h * DE + m16];   // this thread's d == m16

#pragma unroll
    for (int mi = 0; mi < 2; mi++) {
        const int rloc0 = wr * 32 + mi * 16 + q * 4;
#pragma unroll
        for (int ni = 0; ni < 2; ni++) {
            const int cc = c0 + wc * 32 + ni * 16 + m16;
            const int b = cc >> 4;
#pragma unroll
            for (int r = 0; r < 4; r++) {
                const size_t off = (size_t)(r0 + rloc0 + r) * BD + cc;
                const float v = acc[mi][ni][r] + Ph[off] - Qh[off];
                float w = es[rloc0 + r][m16] * (v + fb);
                w += __shfl_xor(w, 1, 64);
                w += __shfl_xor(w, 2, 64);
                w += __shfl_xor(w, 4, 64);
                w += __shfl_xor(w, 8, 64);
                if (m16 == 0)
                    atomicAdd(out + (size_t)b * NN + (r0 + rloc0 + r), mwh * w);
            }
        }
    }
}

extern "C" void kernel_launch(void* const* d_in, const int* in_sizes, int n_in,
                              void* d_out, int out_size, void* d_ws, size_t ws_size,
                              hipStream_t stream)
{
    const float* x          = (const float*)d_in[0];
    const float* psi_emb    = (const float*)d_in[1];
    const float* psi        = (const float*)d_in[2];
    const float* W_q        = (const float*)d_in[3];
    const float* W_k        = (const float*)d_in[4];
    const float* attn_alpha = (const float*)d_in[5];
    const float* F_w        = (const float*)d_in[6];
    const float* f_b        = (const float*)d_in[7];
    const float* head_mix   = (const float*)d_in[8];
    float* out = (float*)d_out;

    short* At  = (short*)d_ws;                 // 4,194,304 bf16 (tiled, per-h 1,048,576)
    short* xt  = At + 4194304;                 // 4,194,304
    short* wtt = xt + 4194304;                 // 32,768
    short* g3t = wtt + 32768;                  // 2,097,152
    short* b2t = g3t + 2097152;                // 2,097,152
    short* b1t = b2t + 2097152;                // 2,097,152
    short* bnt = b1t + 2097152;                // 1,048,576
    short* ant = bnt + 1048576;                // 4,194,304
    float* Gs  = (float*)(ant + 4194304);      // 16 slabs (k*4+h) x 524,288 fp32
    float* b2  = Gs + 16 * (size_t)NS;         // HH*NS
    float* partials = b2 + (size_t)HH * NS;    // 81,920 fp32

    const size_t need_bytes =
        (size_t)(4194304 + 4194304 + 32768 + 2097152 + 2097152 + 2097152 + 1048576 + 4194304) * 2 +
        (size_t)(16 * (size_t)NS + HH * NS + 81920) * 4;
    if (ws_size < need_bytes) return;

    hipMemsetAsync(out, 0, (size_t)out_size * sizeof(float), stream);
    phase1<<<784, 256, 0, stream>>>(psi_emb, psi, W_q, W_k, x, F_w,
                                    bnt, ant, partials, xt, wtt);
    phase2<<<1280, 256, 0, stream>>>(xt, wtt, Gs, g3t, bnt, ant, partials,
                                     attn_alpha, At);

    const dim3 gg(BD / 64, NN / 64, HH);
    // b2 = G2 + 2*A@G3
    gemm_mf<<<gg, 256, 0, stream>>>(At, g3t, Gs + 8 * (size_t)NS, Gs + 8 * (size_t)NS,
                                    b2, b2t, 2.f, 1.f, 0.f, 1, 1);
    // b1 = G1 + 2*A@b2 - G3   (bf16 b1t only)
    gemm_mf<<<gg, 256, 0, stream>>>(At, b2t, Gs + 4 * (size_t)NS, Gs + 12 * (size_t)NS,
                                    b2 /*unused O*/, b1t, 2.f, 1.f, -1.f, 0, 1);
    // out += mw[h] * e·(G0 + A@b1 - b2 + fb)   (fused, atomics)
    gemm3_out<<<gg, 256, 0, stream>>>(At, b1t, Gs, b2, psi_emb, f_b, head_mix, out);
}

// Round 8
// 155.863 us; speedup vs baseline: 1.4294x; 1.1105x over previous
//
#include <hip/hip_runtime.h>
#include <cstdint>

#define NN 1024
#define BB 32
#define LL 128
#define DE 16
#define HH 4
#define K1 4
#define BD 512
#define NS 524288   // NN*BD elements per head slab

using bf16x8 = __attribute__((ext_vector_type(8))) short;
using f32x4  = __attribute__((ext_vector_type(4))) float;

__device__ inline unsigned short f2bf(float f) {
    unsigned u = __builtin_bit_cast(unsigned, f);
    u += 0x7FFFu + ((u >> 16) & 1u);          // round-to-nearest-even
    return (unsigned short)(u >> 16);
}
__device__ inline float bf2f(unsigned short u) {
    return __builtin_bit_cast(float, (unsigned)u << 16);
}

struct LogitsSmem {
    float ejs[64][17];
    float eis[64][17];
    float kjs[64][64];
    float qis[4][64][17];
    float part[4][5][64];
    float wq[1024];
    float wk[1024];
};
struct XtSmem { float xs[64][128]; };

// ================================================================ PHASE 1
// logits (256) | xt_cast (512) | wtt_cast (16) | zero-out (16) = 800 blocks.
__global__ __launch_bounds__(256) void phase1(
    const float* __restrict__ psi_emb, const float* __restrict__ psi_p,
    const float* __restrict__ W_q, const float* __restrict__ W_k,
    const float* __restrict__ x, const float* __restrict__ F_w,
    short* __restrict__ bnt, short* __restrict__ ant, float* __restrict__ partials,
    short* __restrict__ xt, short* __restrict__ wtt, float* __restrict__ out)
{
    __shared__ __align__(16) char smem_raw[sizeof(LogitsSmem)];
    const int bid = blockIdx.x;
    const int tid = threadIdx.x;

    if (bid < 256) {
        // ---------------- logits role (inline Q/K projection)
        LogitsSmem& S = *(LogitsSmem*)smem_raw;
        const int jb = bid & 15, ib = bid >> 4;
        const int i0 = ib * 64, j0 = jb * 64;
        {
            const int row = tid >> 2, dq = (tid & 3) * 4;
            const float4 vj = *(const float4*)(psi_emb + (j0 + row) * DE + dq);
            S.ejs[row][dq] = vj.x; S.ejs[row][dq + 1] = vj.y;
            S.ejs[row][dq + 2] = vj.z; S.ejs[row][dq + 3] = vj.w;
            const float4 vi = *(const float4*)(psi_emb + (i0 + row) * DE + dq);
            S.eis[row][dq] = vi.x; S.eis[row][dq + 1] = vi.y;
            S.eis[row][dq + 2] = vi.z; S.eis[row][dq + 3] = vi.w;
            *(float4*)&S.wq[tid * 4] = *(const float4*)(W_q + tid * 4);
            *(float4*)&S.wk[tid * 4] = *(const float4*)(W_k + tid * 4);
        }
        __syncthreads();
#pragma unroll
        for (int rep = 0; rep < 16; rep++) {
            const int idx = rep * 256 + tid;
            const int row = idx >> 6, hm = idx & 63;
            float qv = 0.f, kv = 0.f;
#pragma unroll
            for (int d = 0; d < DE; d++) {
                qv += S.eis[row][d] * S.wq[d * 64 + hm];
                kv += S.ejs[row][d] * S.wk[d * 64 + hm];
            }
            S.qis[hm >> 4][row][hm & 15] = qv;
            S.kjs[row][hm] = kv;
        }
        __syncthreads();

        const int i = tid & 63, jg = tid >> 6;
        const float psi = psi_p[0];
        float er[DE];
#pragma unroll
        for (int d = 0; d < DE; d++) er[d] = S.eis[i][d];

        float sb = 0.f, sa[HH] = {0.f, 0.f, 0.f, 0.f};
#pragma unroll
        for (int g = 0; g < 2; g++) {
            unsigned short bw[8];
#pragma unroll
            for (int r = 0; r < 8; r++) {
                const int j = jg * 16 + g * 8 + r;
                float d2 = 0.f;
#pragma unroll
                for (int d = 0; d < DE; d++) { const float t = er[d] - S.ejs[j][d]; d2 += t * t; }
                const float bn = __expf(__expf(-psi * d2));
                sb += bn;
                bw[r] = f2bf(bn);
            }
            uint4 pk;
            pk.x = bw[0] | ((unsigned)bw[1] << 16);
            pk.y = bw[2] | ((unsigned)bw[3] << 16);
            pk.z = bw[4] | ((unsigned)bw[5] << 16);
            pk.w = bw[6] | ((unsigned)bw[7] << 16);
            const size_t toff = (size_t)((j0 + jg * 16 + g * 8) >> 3) * 8192 + (size_t)(i0 + i) * 8;
            *(uint4*)(bnt + toff) = pk;
        }
#pragma unroll
        for (int h = 0; h < HH; h++) {
            float qr[DE];
#pragma unroll
            for (int m = 0; m < DE; m++) qr[m] = S.qis[h][i][m];
#pragma unroll
            for (int g = 0; g < 2; g++) {
                unsigned short aw[8];
#pragma unroll
                for (int r = 0; r < 8; r++) {
                    const int j = jg * 16 + g * 8 + r;
                    float dot = 0.f;
#pragma unroll
                    for (int m = 0; m < DE; m++) dot += qr[m] * S.kjs[j][h * DE + m];
                    const float an = __expf(dot * 0.25f);
                    sa[h] += an;
                    aw[r] = f2bf(an);
                }
                uint4 pk;
                pk.x = aw[0] | ((unsigned)aw[1] << 16);
                pk.y = aw[2] | ((unsigned)aw[3] << 16);
                pk.z = aw[4] | ((unsigned)aw[5] << 16);
                pk.w = aw[6] | ((unsigned)aw[7] << 16);
                const size_t toff = (size_t)((j0 + jg * 16 + g * 8) >> 3) * 8192 + (size_t)(i0 + i) * 8;
                *(uint4*)(ant + (size_t)h * 1048576 + toff) = pk;
            }
        }
        S.part[jg][0][i] = sb;
#pragma unroll
        for (int h = 0; h < HH; h++) S.part[jg][1 + h][i] = sa[h];
        __syncthreads();
        if (tid < 64) {
#pragma unroll
            for (int s = 0; s < 5; s++) {
                const float v = S.part[0][s][tid] + S.part[1][s][tid] +
                                S.part[2][s][tid] + S.part[3][s][tid];
                partials[(size_t)jb * 5120 + (size_t)s * 1024 + i0 + tid] = v;
            }
        }
    } else if (bid < 768) {
        // ---------------- xt_cast role
        XtSmem& X = *(XtSmem*)smem_raw;
        const int idx = bid - 256;
        const int m0 = (idx & 15) * 64;
        const int b  = idx >> 4;
        for (int i = tid; i < 2048; i += 256) {
            const int row = i >> 5, lq = i & 31;
            *(float4*)&X.xs[row][lq * 4] =
                *(const float4*)(x + ((size_t)(b * NN + m0 + row)) * LL + lq * 4);
        }
        __syncthreads();
        for (int j = tid; j < 1024; j += 256) {
            const int m = j & 63, lc = j >> 6;
            const float* s = &X.xs[m][lc * 8];
            uint4 pk;
            pk.x = f2bf(s[0]) | ((unsigned)f2bf(s[1]) << 16);
            pk.y = f2bf(s[2]) | ((unsigned)f2bf(s[3]) << 16);
            pk.z = f2bf(s[4]) | ((unsigned)f2bf(s[5]) << 16);
            pk.w = f2bf(s[6]) | ((unsigned)f2bf(s[7]) << 16);
            *(uint4*)(xt + (size_t)b * 131072 + (size_t)lc * 8192 + (size_t)(m0 + m) * 8) = pk;
        }
    } else if (bid < 784) {
        // ---------------- wtt_cast role
        const int j = (bid - 768) * 256 + tid;
        const int lc = j >> 8, c = j & 255;
        const int h = c >> 6, k = (c >> 4) & 3, d = c & 15;
        const float* s = F_w + (size_t)((h * DE + d) * K1 + k) * LL + lc * 8;
        uint4 pk;
        pk.x = f2bf(s[0]) | ((unsigned)f2bf(s[1]) << 16);
        pk.y = f2bf(s[2]) | ((unsigned)f2bf(s[3]) << 16);
        pk.z = f2bf(s[4]) | ((unsigned)f2bf(s[5]) << 16);
        pk.w = f2bf(s[6]) | ((unsigned)f2bf(s[7]) << 16);
        *(uint4*)(wtt + (size_t)lc * 2048 + (size_t)c * 8) = pk;
    } else {
        // ---------------- zero-out role (out is poisoned 0xAA each launch)
        const int idx = (bid - 784) * 256 + tid;       // 4096 threads, 8 floats each
        const float4 z = {0.f, 0.f, 0.f, 0.f};
        *(float4*)(out + (size_t)idx * 8) = z;
        *(float4*)(out + (size_t)idx * 8 + 4) = z;
    }
}

// ================================================================ PHASE 2
// g_mfma (1024 blocks, all-bf16 tiled Gt output) + blend (256 blocks).
__global__ __launch_bounds__(256) void phase2(
    const short* __restrict__ xt, const short* __restrict__ wtt,
    short* __restrict__ Gt,
    const short* __restrict__ bnt, const short* __restrict__ ant,
    const float* __restrict__ partials, const float* __restrict__ alpha_p,
    short* __restrict__ At)
{
    const int bid = blockIdx.x;
    const int tid = threadIdx.x;
    __shared__ float sums_l[5][64];

    if (bid < 1024) {
        // ---------------- g_mfma role
        const int cb = bid & 3;
        const int m0 = ((bid >> 2) & 15) * 64;
        const int bp = bid >> 6;
        const int wave = tid >> 6, lane = tid & 63;
        const int b  = bp * 2 + (wave >> 1);
        const int wc = wave & 1;
        const int q = lane >> 4, m16 = lane & 15;
        const short* xb = xt + (size_t)b * 131072;

        f32x4 acc[4][2];
#pragma unroll
        for (int mi = 0; mi < 4; mi++)
#pragma unroll
            for (int ni = 0; ni < 2; ni++) acc[mi][ni] = (f32x4){0.f, 0.f, 0.f, 0.f};

#pragma unroll
        for (int ks = 0; ks < 4; ks++) {
            const int kc = ks * 4 + q;
            bf16x8 a[4], bb[2];
#pragma unroll
            for (int mi = 0; mi < 4; mi++)
                a[mi] = *(const bf16x8*)(xb + (size_t)kc * 8192 + (size_t)(m0 + mi * 16 + m16) * 8);
#pragma unroll
            for (int ni = 0; ni < 2; ni++)
                bb[ni] = *(const bf16x8*)(wtt + (size_t)kc * 2048 +
                                          (size_t)(cb * 64 + wc * 32 + ni * 16 + m16) * 8);
#pragma unroll
            for (int mi = 0; mi < 4; mi++)
#pragma unroll
                for (int ni = 0; ni < 2; ni++)
                    acc[mi][ni] = __builtin_amdgcn_mfma_f32_16x16x32_bf16(a[mi], bb[ni], acc[mi][ni], 0, 0, 0);
        }

        // bf16 tiled stores only (full-line coalesced); slab = kk*4+hh
#pragma unroll
        for (int ni = 0; ni < 2; ni++) {
            const int cc = cb * 64 + wc * 32 + ni * 16 + m16;
            const int kk = (cc >> 4) & 3, hh = cc >> 6;
            const int col512 = b * 16 + (cc & 15);
            short* gdst = Gt + (size_t)(kk * 4 + hh) * 524288;
#pragma unroll
            for (int mi = 0; mi < 4; mi++) {
                const int row0 = m0 + mi * 16 + q * 4;
                ushort4 pk;
                pk.x = f2bf(acc[mi][ni][0]); pk.y = f2bf(acc[mi][ni][1]);
                pk.z = f2bf(acc[mi][ni][2]); pk.w = f2bf(acc[mi][ni][3]);
                *(ushort4*)(gdst + ((size_t)(row0 >> 3) * 512 + col512) * 8 + (row0 & 7)) = pk;
            }
        }
    } else {
        // ---------------- blend role
        const int idx = bid - 1024;
        const int jb = idx & 15, ib = idx >> 4;
        const int i0 = ib * 64, j0 = jb * 64;
        const int lane = tid & 63, w = tid >> 6;
        {
            float acc = 0.f;
#pragma unroll
            for (int jb2 = 0; jb2 < 16; jb2++)
                acc += partials[(size_t)jb2 * 5120 + (size_t)w * 1024 + i0 + lane];
            sums_l[w][lane] = acc;
            if (w == 0) {
                float a4 = 0.f;
#pragma unroll
                for (int jb2 = 0; jb2 < 16; jb2++)
                    a4 += partials[(size_t)jb2 * 5120 + 4 * 1024 + i0 + lane];
                sums_l[4][lane] = a4;
            }
        }
        __syncthreads();
        const int i = lane, jg = w;
        const float alpha = 1.f / (1.f + __expf(-alpha_p[0]));
        const float ibs = alpha / sums_l[0][i];
        float ias[HH];
#pragma unroll
        for (int h = 0; h < HH; h++) ias[h] = (1.f - alpha) / sums_l[1 + h][i];

#pragma unroll
        for (int g = 0; g < 2; g++) {
            const size_t toff = (size_t)((j0 + jg * 16 + g * 8) >> 3) * 8192 + (size_t)(i0 + i) * 8;
            const uint4 bp = *(const uint4*)(bnt + toff);
            float bnv[8];
            bnv[0] = bf2f(bp.x & 0xFFFF); bnv[1] = bf2f(bp.x >> 16);
            bnv[2] = bf2f(bp.y & 0xFFFF); bnv[3] = bf2f(bp.y >> 16);
            bnv[4] = bf2f(bp.z & 0xFFFF); bnv[5] = bf2f(bp.z >> 16);
            bnv[6] = bf2f(bp.w & 0xFFFF); bnv[7] = bf2f(bp.w >> 16);
#pragma unroll
            for (int h = 0; h < HH; h++) {
                const uint4 ap = *(const uint4*)(ant + (size_t)h * 1048576 + toff);
                float av[8];
                av[0] = bf2f(ap.x & 0xFFFF); av[1] = bf2f(ap.x >> 16);
                av[2] = bf2f(ap.y & 0xFFFF); av[3] = bf2f(ap.y >> 16);
                av[4] = bf2f(ap.z & 0xFFFF); av[5] = bf2f(ap.z >> 16);
                av[6] = bf2f(ap.w & 0xFFFF); av[7] = bf2f(ap.w >> 16);
                unsigned short ow[8];
#pragma unroll
                for (int r = 0; r < 8; r++) ow[r] = f2bf(ibs * bnv[r] + ias[h] * av[r]);
                uint4 pk;
                pk.x = ow[0] | ((unsigned)ow[1] << 16);
                pk.y = ow[2] | ((unsigned)ow[3] << 16);
                pk.z = ow[4] | ((unsigned)ow[5] << 16);
                pk.w = ow[6] | ((unsigned)ow[7] << 16);
                *(uint4*)(At + (size_t)h * 1048576 + toff) = pk;
            }
        }
    }
}

// ================================================================ Clenshaw GEMM (MFMA, all-bf16 I/O)
// Ot = bf16( scale*(A@B) + pc*P + qc*Q ), P/Q/Ot all bf16-tiled, hs=524288/head.
__global__ __launch_bounds__(256) void gemm_mf(
    const short* __restrict__ At, const short* __restrict__ Bt,
    const short* __restrict__ Pt, const short* __restrict__ Qt,
    short* __restrict__ Ot, float scale, float pc, float qc)
{
    const int h = blockIdx.z;
    const short* Ah = At + (size_t)h * 1048576;
    const short* Bh = Bt + (size_t)h * 524288;
    const short* Ph = Pt + (size_t)h * 524288;
    const short* Qh = Qt + (size_t)h * 524288;
    short* Oh = Ot + (size_t)h * 524288;

    const int c0 = blockIdx.x * 64;
    const int r0 = blockIdx.y * 64;
    const int tid = threadIdx.x;
    const int wave = tid >> 6, lane = tid & 63;
    const int q = lane >> 4, m16 = lane & 15;
    const int wr = wave >> 1, wc = wave & 1;

    __shared__ __align__(16) short As[2][2048];
    __shared__ __align__(16) short Bs[2][2048];

    {
        uint4 ra = *(const uint4*)(Ah + ((size_t)wave * 1024 + r0 + lane) * 8);
        uint4 rb = *(const uint4*)(Bh + ((size_t)wave * 512 + c0 + lane) * 8);
        *(uint4*)&As[0][wave * 512 + lane * 8] = ra;
        *(uint4*)&Bs[0][wave * 512 + lane * 8] = rb;
    }
    __syncthreads();

    f32x4 acc[2][2];
#pragma unroll
    for (int mi = 0; mi < 2; mi++)
#pragma unroll
        for (int ni = 0; ni < 2; ni++) acc[mi][ni] = (f32x4){0.f, 0.f, 0.f, 0.f};

    int buf = 0;
    for (int k0 = 32; k0 <= 1024; k0 += 32) {
        uint4 na, nb;
        const bool more = (k0 < 1024);
        if (more) {
            na = *(const uint4*)(Ah + (((size_t)(k0 >> 3) + wave) * 1024 + r0 + lane) * 8);
            nb = *(const uint4*)(Bh + (((size_t)(k0 >> 3) + wave) * 512 + c0 + lane) * 8);
        }
        bf16x8 af0 = *(const bf16x8*)&As[buf][q * 512 + (wr * 32 + m16) * 8];
        bf16x8 af1 = *(const bf16x8*)&As[buf][q * 512 + (wr * 32 + 16 + m16) * 8];
        bf16x8 bf0 = *(const bf16x8*)&Bs[buf][q * 512 + (wc * 32 + m16) * 8];
        bf16x8 bf1 = *(const bf16x8*)&Bs[buf][q * 512 + (wc * 32 + 16 + m16) * 8];
        acc[0][0] = __builtin_amdgcn_mfma_f32_16x16x32_bf16(af0, bf0, acc[0][0], 0, 0, 0);
        acc[0][1] = __builtin_amdgcn_mfma_f32_16x16x32_bf16(af0, bf1, acc[0][1], 0, 0, 0);
        acc[1][0] = __builtin_amdgcn_mfma_f32_16x16x32_bf16(af1, bf0, acc[1][0], 0, 0, 0);
        acc[1][1] = __builtin_amdgcn_mfma_f32_16x16x32_bf16(af1, bf1, acc[1][1], 0, 0, 0);
        if (more) {
            const int nx = buf ^ 1;
            *(uint4*)&As[nx][wave * 512 + lane * 8] = na;
            *(uint4*)&Bs[nx][wave * 512 + lane * 8] = nb;
            __syncthreads();
            buf = nx;
        }
    }

#pragma unroll
    for (int mi = 0; mi < 2; mi++) {
        const int row0 = r0 + wr * 32 + mi * 16 + q * 4;
#pragma unroll
        for (int ni = 0; ni < 2; ni++) {
            const int cc = c0 + wc * 32 + ni * 16 + m16;
            const size_t off = ((size_t)(row0 >> 3) * 512 + cc) * 8 + (row0 & 7);
            const ushort4 pv = *(const ushort4*)(Ph + off);
            float v[4];
            v[0] = scale * acc[mi][ni][0] + pc * bf2f(pv.x);
            v[1] = scale * acc[mi][ni][1] + pc * bf2f(pv.y);
            v[2] = scale * acc[mi][ni][2] + pc * bf2f(pv.z);
            v[3] = scale * acc[mi][ni][3] + pc * bf2f(pv.w);
            if (qc != 0.f) {
                const ushort4 qv = *(const ushort4*)(Qh + off);
                v[0] += qc * bf2f(qv.x); v[1] += qc * bf2f(qv.y);
                v[2] += qc * bf2f(qv.z); v[3] += qc * bf2f(qv.w);
            }
            ushort4 pk;
            pk.x = f2bf(v[0]); pk.y = f2bf(v[1]); pk.z = f2bf(v[2]); pk.w = f2bf(v[3]);
            *(ushort4*)(Oh + off) = pk;
        }
    }
}

// ================================================================ GEMM3 + fused output contraction
// Sf = G0 + A@b1 - b2 in-register (P=G0t, Q=b2t, both bf16-tiled); epilogue
// contracts with psi_emb and f_b, shfl-reduces over 16 d-lanes, atomicAdds
// mw[h]*sum into out (zeroed by phase1).
__global__ __launch_bounds__(256) void gemm3_out(
    const short* __restrict__ At, const short* __restrict__ Bt,
    const short* __restrict__ Pt, const short* __restrict__ Qt,
    const float* __restrict__ psi_emb, const float* __restrict__ f_b,
    const float* __restrict__ head_mix, float* __restrict__ out)
{
    const int h = blockIdx.z;
    const short* Ah = At + (size_t)h * 1048576;
    const short* Bh = Bt + (size_t)h * 524288;
    const short* Ph = Pt + (size_t)h * 524288;
    const short* Qh = Qt + (size_t)h * 524288;

    const int c0 = blockIdx.x * 64;
    const int r0 = blockIdx.y * 64;
    const int tid = threadIdx.x;
    const int wave = tid >> 6, lane = tid & 63;
    const int q = lane >> 4, m16 = lane & 15;
    const int wr = wave >> 1, wc = wave & 1;

    __shared__ __align__(16) short As[2][2048];
    __shared__ __align__(16) short Bs[2][2048];
    __shared__ float es[64][17];

    {
        uint4 ra = *(const uint4*)(Ah + ((size_t)wave * 1024 + r0 + lane) * 8);
        uint4 rb = *(const uint4*)(Bh + ((size_t)wave * 512 + c0 + lane) * 8);
        *(uint4*)&As[0][wave * 512 + lane * 8] = ra;
        *(uint4*)&Bs[0][wave * 512 + lane * 8] = rb;
        const int row = tid >> 2, dq = (tid & 3) * 4;
        const float4 ev = *(const float4*)(psi_emb + (size_t)(r0 + row) * DE + dq);
        es[row][dq] = ev.x; es[row][dq + 1] = ev.y;
        es[row][dq + 2] = ev.z; es[row][dq + 3] = ev.w;
    }
    __syncthreads();

    f32x4 acc[2][2];
#pragma unroll
    for (int mi = 0; mi < 2; mi++)
#pragma unroll
        for (int ni = 0; ni < 2; ni++) acc[mi][ni] = (f32x4){0.f, 0.f, 0.f, 0.f};

    int buf = 0;
    for (int k0 = 32; k0 <= 1024; k0 += 32) {
        uint4 na, nb;
        const bool more = (k0 < 1024);
        if (more) {
            na = *(const uint4*)(Ah + (((size_t)(k0 >> 3) + wave) * 1024 + r0 + lane) * 8);
            nb = *(const uint4*)(Bh + (((size_t)(k0 >> 3) + wave) * 512 + c0 + lane) * 8);
        }
        bf16x8 af0 = *(const bf16x8*)&As[buf][q * 512 + (wr * 32 + m16) * 8];
        bf16x8 af1 = *(const bf16x8*)&As[buf][q * 512 + (wr * 32 + 16 + m16) * 8];
        bf16x8 bf0 = *(const bf16x8*)&Bs[buf][q * 512 + (wc * 32 + m16) * 8];
        bf16x8 bf1 = *(const bf16x8*)&Bs[buf][q * 512 + (wc * 32 + 16 + m16) * 8];
        acc[0][0] = __builtin_amdgcn_mfma_f32_16x16x32_bf16(af0, bf0, acc[0][0], 0, 0, 0);
        acc[0][1] = __builtin_amdgcn_mfma_f32_16x16x32_bf16(af0, bf1, acc[0][1], 0, 0, 0);
        acc[1][0] = __builtin_amdgcn_mfma_f32_16x16x32_bf16(af1, bf0, acc[1][0], 0, 0, 0);
        acc[1][1] = __builtin_amdgcn_mfma_f32_16x16x32_bf16(af1, bf1, acc[1][1], 0, 0, 0);
        if (more) {
            const int nx = buf ^ 1;
            *(uint4*)&As[nx][wave * 512 + lane * 8] = na;
            *(uint4*)&Bs[nx][wave * 512 + lane * 8] = nb;
            __syncthreads();
            buf = nx;
        }
    }

    const float hm0 = head_mix[0], hm1 = head_mix[1], hm2 = head_mix[2], hm3 = head_mix[3];
    const float mx = fmaxf(fmaxf(hm0, hm1), fmaxf(hm2, hm3));
    const float w0 = expf(hm0 - mx), w1 = expf(hm1 - mx), w2 = expf(hm2 - mx), w3 = expf(hm3 - mx);
    const float isum = 1.f / (w0 + w1 + w2 + w3);
    const float mwh = (h == 0 ? w0 : h == 1 ? w1 : h == 2 ? w2 : w3) * isum;
    const float fb = f_b[h * DE + m16];

#pragma unroll
    for (int mi = 0; mi < 2; mi++) {
        const int rloc0 = wr * 32 + mi * 16 + q * 4;
        const int row0 = r0 + rloc0;
#pragma unroll
        for (int ni = 0; ni < 2; ni++) {
            const int cc = c0 + wc * 32 + ni * 16 + m16;
            const int b = cc >> 4;
            const size_t off = ((size_t)(row0 >> 3) * 512 + cc) * 8 + (row0 & 7);
            const ushort4 pv = *(const ushort4*)(Ph + off);
            const ushort4 qv = *(const ushort4*)(Qh + off);
            float v[4];
            v[0] = acc[mi][ni][0] + bf2f(pv.x) - bf2f(qv.x);
            v[1] = acc[mi][ni][1] + bf2f(pv.y) - bf2f(qv.y);
            v[2] = acc[mi][ni][2] + bf2f(pv.z) - bf2f(qv.z);
            v[3] = acc[mi][ni][3] + bf2f(pv.w) - bf2f(qv.w);
#pragma unroll
            for (int r = 0; r < 4; r++) {
                float w = es[rloc0 + r][m16] * (v[r] + fb);
                w += __shfl_xor(w, 1, 64);
                w += __shfl_xor(w, 2, 64);
                w += __shfl_xor(w, 4, 64);
                w += __shfl_xor(w, 8, 64);
                if (m16 == 0)
                    atomicAdd(out + (size_t)b * NN + (row0 + r), mwh * w);
            }
        }
    }
}

extern "C" void kernel_launch(void* const* d_in, const int* in_sizes, int n_in,
                              void* d_out, int out_size, void* d_ws, size_t ws_size,
                              hipStream_t stream)
{
    const float* x          = (const float*)d_in[0];
    const float* psi_emb    = (const float*)d_in[1];
    const float* psi        = (const float*)d_in[2];
    const float* W_q        = (const float*)d_in[3];
    const float* W_k        = (const float*)d_in[4];
    const float* attn_alpha = (const float*)d_in[5];
    const float* F_w        = (const float*)d_in[6];
    const float* f_b        = (const float*)d_in[7];
    const float* head_mix   = (const float*)d_in[8];
    float* out = (float*)d_out;

    short* At  = (short*)d_ws;                 // 4,194,304 shorts (per-h 1,048,576)
    short* xt  = At + 4194304;                 // 4,194,304
    short* wtt = xt + 4194304;                 // 32,768
    short* Gt  = wtt + 32768;                  // 16 slabs (k*4+h) x 524,288 shorts
    short* b2t = Gt + 8388608;                 // 2,097,152
    short* b1t = b2t + 2097152;                // 2,097,152
    short* bnt = b1t + 2097152;                // 1,048,576
    short* ant = bnt + 1048576;                // 4,194,304
    float* partials = (float*)(ant + 4194304); // 81,920 fp32

    const size_t need_bytes =
        (size_t)(4194304 + 4194304 + 32768 + 8388608 + 2097152 + 2097152 + 1048576 + 4194304) * 2 +
        (size_t)81920 * 4;
    if (ws_size < need_bytes) return;

    phase1<<<800, 256, 0, stream>>>(psi_emb, psi, W_q, W_k, x, F_w,
                                    bnt, ant, partials, xt, wtt, out);
    phase2<<<1280, 256, 0, stream>>>(xt, wtt, Gt, bnt, ant, partials,
                                     attn_alpha, At);

    const dim3 gg(BD / 64, NN / 64, HH);
    // b2t = bf16(G2 + 2*A@G3)
    gemm_mf<<<gg, 256, 0, stream>>>(At, Gt + 12 * (size_t)524288, Gt + 8 * (size_t)524288,
                                    Gt /*unused*/, b2t, 2.f, 1.f, 0.f);
    // b1t = bf16(G1 + 2*A@b2 - G3)
    gemm_mf<<<gg, 256, 0, stream>>>(At, b2t, Gt + 4 * (size_t)524288,
                                    Gt + 12 * (size_t)524288, b1t, 2.f, 1.f, -1.f);
    // out += mw[h] * e·(G0 + A@b1 - b2 + fb)
    gemm3_out<<<gg, 256, 0, stream>>>(At, b1t, Gt, b2t, psi_emb, f_b, head_mix, out);
}

// Round 9
// 151.791 us; speedup vs baseline: 1.4677x; 1.0268x over previous
//
#include <hip/hip_runtime.h>
#include <cstdint>

#define NN 1024
#define BB 32
#define LL 128
#define DE 16
#define HH 4
#define K1 4
#define BD 512
#define NS 524288   // NN*BD elements per head slab

using bf16x8 = __attribute__((ext_vector_type(8))) short;
using f32x4  = __attribute__((ext_vector_type(4))) float;

__device__ inline unsigned short f2bf(float f) {
    unsigned u = __builtin_bit_cast(unsigned, f);
    u += 0x7FFFu + ((u >> 16) & 1u);          // round-to-nearest-even
    return (unsigned short)(u >> 16);
}
__device__ inline float bf2f(unsigned short u) {
    return __builtin_bit_cast(float, (unsigned)u << 16);
}

struct LogitsSmem {
    float ejs[64][17];
    float eis[64][17];
    float kjs[64][64];
    float qis[4][64][17];
    float part[4][5][64];
    float wq[1024];
    float wk[1024];
};
struct XtSmem { float xs[64][128]; };

// ================================================================ PHASE 1
// logits (256) | xt_cast (512) | wtt_cast (16) | zero-out (16) = 800 blocks.
__global__ __launch_bounds__(256) void phase1(
    const float* __restrict__ psi_emb, const float* __restrict__ psi_p,
    const float* __restrict__ W_q, const float* __restrict__ W_k,
    const float* __restrict__ x, const float* __restrict__ F_w,
    short* __restrict__ bnt, short* __restrict__ ant, float* __restrict__ partials,
    short* __restrict__ xt, short* __restrict__ wtt, float* __restrict__ out)
{
    __shared__ __align__(16) char smem_raw[sizeof(LogitsSmem)];
    const int bid = blockIdx.x;
    const int tid = threadIdx.x;

    if (bid < 256) {
        // ---------------- logits role (inline Q/K projection)
        LogitsSmem& S = *(LogitsSmem*)smem_raw;
        const int jb = bid & 15, ib = bid >> 4;
        const int i0 = ib * 64, j0 = jb * 64;
        {
            const int row = tid >> 2, dq = (tid & 3) * 4;
            const float4 vj = *(const float4*)(psi_emb + (j0 + row) * DE + dq);
            S.ejs[row][dq] = vj.x; S.ejs[row][dq + 1] = vj.y;
            S.ejs[row][dq + 2] = vj.z; S.ejs[row][dq + 3] = vj.w;
            const float4 vi = *(const float4*)(psi_emb + (i0 + row) * DE + dq);
            S.eis[row][dq] = vi.x; S.eis[row][dq + 1] = vi.y;
            S.eis[row][dq + 2] = vi.z; S.eis[row][dq + 3] = vi.w;
            *(float4*)&S.wq[tid * 4] = *(const float4*)(W_q + tid * 4);
            *(float4*)&S.wk[tid * 4] = *(const float4*)(W_k + tid * 4);
        }
        __syncthreads();
#pragma unroll
        for (int rep = 0; rep < 16; rep++) {
            const int idx = rep * 256 + tid;
            const int row = idx >> 6, hm = idx & 63;
            float qv = 0.f, kv = 0.f;
#pragma unroll
            for (int d = 0; d < DE; d++) {
                qv += S.eis[row][d] * S.wq[d * 64 + hm];
                kv += S.ejs[row][d] * S.wk[d * 64 + hm];
            }
            S.qis[hm >> 4][row][hm & 15] = qv;
            S.kjs[row][hm] = kv;
        }
        __syncthreads();

        const int i = tid & 63, jg = tid >> 6;
        const float psi = psi_p[0];
        float er[DE];
#pragma unroll
        for (int d = 0; d < DE; d++) er[d] = S.eis[i][d];

        float sb = 0.f, sa[HH] = {0.f, 0.f, 0.f, 0.f};
#pragma unroll
        for (int g = 0; g < 2; g++) {
            unsigned short bw[8];
#pragma unroll
            for (int r = 0; r < 8; r++) {
                const int j = jg * 16 + g * 8 + r;
                float d2 = 0.f;
#pragma unroll
                for (int d = 0; d < DE; d++) { const float t = er[d] - S.ejs[j][d]; d2 += t * t; }
                const float bn = __expf(__expf(-psi * d2));
                sb += bn;
                bw[r] = f2bf(bn);
            }
            uint4 pk;
            pk.x = bw[0] | ((unsigned)bw[1] << 16);
            pk.y = bw[2] | ((unsigned)bw[3] << 16);
            pk.z = bw[4] | ((unsigned)bw[5] << 16);
            pk.w = bw[6] | ((unsigned)bw[7] << 16);
            const size_t toff = (size_t)((j0 + jg * 16 + g * 8) >> 3) * 8192 + (size_t)(i0 + i) * 8;
            *(uint4*)(bnt + toff) = pk;
        }
#pragma unroll
        for (int h = 0; h < HH; h++) {
            float qr[DE];
#pragma unroll
            for (int m = 0; m < DE; m++) qr[m] = S.qis[h][i][m];
#pragma unroll
            for (int g = 0; g < 2; g++) {
                unsigned short aw[8];
#pragma unroll
                for (int r = 0; r < 8; r++) {
                    const int j = jg * 16 + g * 8 + r;
                    float dot = 0.f;
#pragma unroll
                    for (int m = 0; m < DE; m++) dot += qr[m] * S.kjs[j][h * DE + m];
                    const float an = __expf(dot * 0.25f);
                    sa[h] += an;
                    aw[r] = f2bf(an);
                }
                uint4 pk;
                pk.x = aw[0] | ((unsigned)aw[1] << 16);
                pk.y = aw[2] | ((unsigned)aw[3] << 16);
                pk.z = aw[4] | ((unsigned)aw[5] << 16);
                pk.w = aw[6] | ((unsigned)aw[7] << 16);
                const size_t toff = (size_t)((j0 + jg * 16 + g * 8) >> 3) * 8192 + (size_t)(i0 + i) * 8;
                *(uint4*)(ant + (size_t)h * 1048576 + toff) = pk;
            }
        }
        S.part[jg][0][i] = sb;
#pragma unroll
        for (int h = 0; h < HH; h++) S.part[jg][1 + h][i] = sa[h];
        __syncthreads();
        if (tid < 64) {
#pragma unroll
            for (int s = 0; s < 5; s++) {
                const float v = S.part[0][s][tid] + S.part[1][s][tid] +
                                S.part[2][s][tid] + S.part[3][s][tid];
                partials[(size_t)jb * 5120 + (size_t)s * 1024 + i0 + tid] = v;
            }
        }
    } else if (bid < 768) {
        // ---------------- xt_cast role
        XtSmem& X = *(XtSmem*)smem_raw;
        const int idx = bid - 256;
        const int m0 = (idx & 15) * 64;
        const int b  = idx >> 4;
        for (int i = tid; i < 2048; i += 256) {
            const int row = i >> 5, lq = i & 31;
            *(float4*)&X.xs[row][lq * 4] =
                *(const float4*)(x + ((size_t)(b * NN + m0 + row)) * LL + lq * 4);
        }
        __syncthreads();
        for (int j = tid; j < 1024; j += 256) {
            const int m = j & 63, lc = j >> 6;
            const float* s = &X.xs[m][lc * 8];
            uint4 pk;
            pk.x = f2bf(s[0]) | ((unsigned)f2bf(s[1]) << 16);
            pk.y = f2bf(s[2]) | ((unsigned)f2bf(s[3]) << 16);
            pk.z = f2bf(s[4]) | ((unsigned)f2bf(s[5]) << 16);
            pk.w = f2bf(s[6]) | ((unsigned)f2bf(s[7]) << 16);
            *(uint4*)(xt + (size_t)b * 131072 + (size_t)lc * 8192 + (size_t)(m0 + m) * 8) = pk;
        }
    } else if (bid < 784) {
        // ---------------- wtt_cast role
        const int j = (bid - 768) * 256 + tid;
        const int lc = j >> 8, c = j & 255;
        const int h = c >> 6, k = (c >> 4) & 3, d = c & 15;
        const float* s = F_w + (size_t)((h * DE + d) * K1 + k) * LL + lc * 8;
        uint4 pk;
        pk.x = f2bf(s[0]) | ((unsigned)f2bf(s[1]) << 16);
        pk.y = f2bf(s[2]) | ((unsigned)f2bf(s[3]) << 16);
        pk.z = f2bf(s[4]) | ((unsigned)f2bf(s[5]) << 16);
        pk.w = f2bf(s[6]) | ((unsigned)f2bf(s[7]) << 16);
        *(uint4*)(wtt + (size_t)lc * 2048 + (size_t)c * 8) = pk;
    } else {
        // ---------------- zero-out role (out is poisoned 0xAA each launch)
        const int idx = (bid - 784) * 256 + tid;       // 4096 threads, 8 floats each
        const float4 z = {0.f, 0.f, 0.f, 0.f};
        *(float4*)(out + (size_t)idx * 8) = z;
        *(float4*)(out + (size_t)idx * 8 + 4) = z;
    }
}

// ================================================================ PHASE 2
// g_mfma (1024 blocks, all-bf16 tiled Gt output) + blend (256 blocks).
__global__ __launch_bounds__(256) void phase2(
    const short* __restrict__ xt, const short* __restrict__ wtt,
    short* __restrict__ Gt,
    const short* __restrict__ bnt, const short* __restrict__ ant,
    const float* __restrict__ partials, const float* __restrict__ alpha_p,
    short* __restrict__ At)
{
    const int bid = blockIdx.x;
    const int tid = threadIdx.x;
    __shared__ float sums_l[5][64];

    if (bid < 1024) {
        // ---------------- g_mfma role
        const int cb = bid & 3;
        const int m0 = ((bid >> 2) & 15) * 64;
        const int bp = bid >> 6;
        const int wave = tid >> 6, lane = tid & 63;
        const int b  = bp * 2 + (wave >> 1);
        const int wc = wave & 1;
        const int q = lane >> 4, m16 = lane & 15;
        const short* xb = xt + (size_t)b * 131072;

        f32x4 acc[4][2];
#pragma unroll
        for (int mi = 0; mi < 4; mi++)
#pragma unroll
            for (int ni = 0; ni < 2; ni++) acc[mi][ni] = (f32x4){0.f, 0.f, 0.f, 0.f};

#pragma unroll
        for (int ks = 0; ks < 4; ks++) {
            const int kc = ks * 4 + q;
            bf16x8 a[4], bb[2];
#pragma unroll
            for (int mi = 0; mi < 4; mi++)
                a[mi] = *(const bf16x8*)(xb + (size_t)kc * 8192 + (size_t)(m0 + mi * 16 + m16) * 8);
#pragma unroll
            for (int ni = 0; ni < 2; ni++)
                bb[ni] = *(const bf16x8*)(wtt + (size_t)kc * 2048 +
                                          (size_t)(cb * 64 + wc * 32 + ni * 16 + m16) * 8);
#pragma unroll
            for (int mi = 0; mi < 4; mi++)
#pragma unroll
                for (int ni = 0; ni < 2; ni++)
                    acc[mi][ni] = __builtin_amdgcn_mfma_f32_16x16x32_bf16(a[mi], bb[ni], acc[mi][ni], 0, 0, 0);
        }

        // bf16 tiled stores only (full-line coalesced); slab = kk*4+hh
#pragma unroll
        for (int ni = 0; ni < 2; ni++) {
            const int cc = cb * 64 + wc * 32 + ni * 16 + m16;
            const int kk = (cc >> 4) & 3, hh = cc >> 6;
            const int col512 = b * 16 + (cc & 15);
            short* gdst = Gt + (size_t)(kk * 4 + hh) * 524288;
#pragma unroll
            for (int mi = 0; mi < 4; mi++) {
                const int row0 = m0 + mi * 16 + q * 4;
                ushort4 pk;
                pk.x = f2bf(acc[mi][ni][0]); pk.y = f2bf(acc[mi][ni][1]);
                pk.z = f2bf(acc[mi][ni][2]); pk.w = f2bf(acc[mi][ni][3]);
                *(ushort4*)(gdst + ((size_t)(row0 >> 3) * 512 + col512) * 8 + (row0 & 7)) = pk;
            }
        }
    } else {
        // ---------------- blend role
        const int idx = bid - 1024;
        const int jb = idx & 15, ib = idx >> 4;
        const int i0 = ib * 64, j0 = jb * 64;
        const int lane = tid & 63, w = tid >> 6;
        {
            float acc = 0.f;
#pragma unroll
            for (int jb2 = 0; jb2 < 16; jb2++)
                acc += partials[(size_t)jb2 * 5120 + (size_t)w * 1024 + i0 + lane];
            sums_l[w][lane] = acc;
            if (w == 0) {
                float a4 = 0.f;
#pragma unroll
                for (int jb2 = 0; jb2 < 16; jb2++)
                    a4 += partials[(size_t)jb2 * 5120 + 4 * 1024 + i0 + lane];
                sums_l[4][lane] = a4;
            }
        }
        __syncthreads();
        const int i = lane, jg = w;
        const float alpha = 1.f / (1.f + __expf(-alpha_p[0]));
        const float ibs = alpha / sums_l[0][i];
        float ias[HH];
#pragma unroll
        for (int h = 0; h < HH; h++) ias[h] = (1.f - alpha) / sums_l[1 + h][i];

#pragma unroll
        for (int g = 0; g < 2; g++) {
            const size_t toff = (size_t)((j0 + jg * 16 + g * 8) >> 3) * 8192 + (size_t)(i0 + i) * 8;
            const uint4 bp = *(const uint4*)(bnt + toff);
            float bnv[8];
            bnv[0] = bf2f(bp.x & 0xFFFF); bnv[1] = bf2f(bp.x >> 16);
            bnv[2] = bf2f(bp.y & 0xFFFF); bnv[3] = bf2f(bp.y >> 16);
            bnv[4] = bf2f(bp.z & 0xFFFF); bnv[5] = bf2f(bp.z >> 16);
            bnv[6] = bf2f(bp.w & 0xFFFF); bnv[7] = bf2f(bp.w >> 16);
#pragma unroll
            for (int h = 0; h < HH; h++) {
                const uint4 ap = *(const uint4*)(ant + (size_t)h * 1048576 + toff);
                float av[8];
                av[0] = bf2f(ap.x & 0xFFFF); av[1] = bf2f(ap.x >> 16);
                av[2] = bf2f(ap.y & 0xFFFF); av[3] = bf2f(ap.y >> 16);
                av[4] = bf2f(ap.z & 0xFFFF); av[5] = bf2f(ap.z >> 16);
                av[6] = bf2f(ap.w & 0xFFFF); av[7] = bf2f(ap.w >> 16);
                unsigned short ow[8];
#pragma unroll
                for (int r = 0; r < 8; r++) ow[r] = f2bf(ibs * bnv[r] + ias[h] * av[r]);
                uint4 pk;
                pk.x = ow[0] | ((unsigned)ow[1] << 16);
                pk.y = ow[2] | ((unsigned)ow[3] << 16);
                pk.z = ow[4] | ((unsigned)ow[5] << 16);
                pk.w = ow[6] | ((unsigned)ow[7] << 16);
                *(uint4*)(At + (size_t)h * 1048576 + toff) = pk;
            }
        }
    }
}

// ================================================================ Clenshaw GEMM (MFMA, direct-global fragments)
// R8 post-mortem: LDS staging + per-iter barrier made the GEMM LDS/barrier-
// bound (~4 ds_read_b128 vs 4 MFMA per k-step + vmcnt(0) drain). A/B are
// ALREADY fragment-tiled in global: each 16-lane quad loads 256 B contiguous.
// No LDS, no barriers; unroll 8 gives the scheduler deep outstanding loads.
__global__ __launch_bounds__(256) void gemm_mf(
    const short* __restrict__ At, const short* __restrict__ Bt,
    const short* __restrict__ Pt, const short* __restrict__ Qt,
    short* __restrict__ Ot, float scale, float pc, float qc)
{
    const int h = blockIdx.z;
    const short* Ah = At + (size_t)h * 1048576;
    const short* Bh = Bt + (size_t)h * 524288;
    const short* Ph = Pt + (size_t)h * 524288;
    const short* Qh = Qt + (size_t)h * 524288;
    short* Oh = Ot + (size_t)h * 524288;

    const int c0 = blockIdx.x * 64;
    const int r0 = blockIdx.y * 64;
    const int tid = threadIdx.x;
    const int wave = tid >> 6, lane = tid & 63;
    const int q = lane >> 4, m16 = lane & 15;
    const int wr = wave >> 1, wc = wave & 1;

    // per-lane fragment base pointers (k-chunk q, then advance by 4 chunks/iter)
    const short* Ap = Ah + (size_t)q * 8192 + (size_t)(r0 + wr * 32 + m16) * 8;
    const short* Bp = Bh + (size_t)q * 4096 + (size_t)(c0 + wc * 32 + m16) * 8;

    f32x4 acc[2][2];
#pragma unroll
    for (int mi = 0; mi < 2; mi++)
#pragma unroll
        for (int ni = 0; ni < 2; ni++) acc[mi][ni] = (f32x4){0.f, 0.f, 0.f, 0.f};

#pragma unroll 8
    for (int it = 0; it < 32; it++) {
        const bf16x8 af0 = *(const bf16x8*)(Ap + (size_t)it * 32768);
        const bf16x8 af1 = *(const bf16x8*)(Ap + (size_t)it * 32768 + 128);
        const bf16x8 bf0 = *(const bf16x8*)(Bp + (size_t)it * 16384);
        const bf16x8 bf1 = *(const bf16x8*)(Bp + (size_t)it * 16384 + 128);
        acc[0][0] = __builtin_amdgcn_mfma_f32_16x16x32_bf16(af0, bf0, acc[0][0], 0, 0, 0);
        acc[0][1] = __builtin_amdgcn_mfma_f32_16x16x32_bf16(af0, bf1, acc[0][1], 0, 0, 0);
        acc[1][0] = __builtin_amdgcn_mfma_f32_16x16x32_bf16(af1, bf0, acc[1][0], 0, 0, 0);
        acc[1][1] = __builtin_amdgcn_mfma_f32_16x16x32_bf16(af1, bf1, acc[1][1], 0, 0, 0);
    }

#pragma unroll
    for (int mi = 0; mi < 2; mi++) {
        const int row0 = r0 + wr * 32 + mi * 16 + q * 4;
#pragma unroll
        for (int ni = 0; ni < 2; ni++) {
            const int cc = c0 + wc * 32 + ni * 16 + m16;
            const size_t off = ((size_t)(row0 >> 3) * 512 + cc) * 8 + (row0 & 7);
            const ushort4 pv = *(const ushort4*)(Ph + off);
            float v[4];
            v[0] = scale * acc[mi][ni][0] + pc * bf2f(pv.x);
            v[1] = scale * acc[mi][ni][1] + pc * bf2f(pv.y);
            v[2] = scale * acc[mi][ni][2] + pc * bf2f(pv.z);
            v[3] = scale * acc[mi][ni][3] + pc * bf2f(pv.w);
            if (qc != 0.f) {
                const ushort4 qv = *(const ushort4*)(Qh + off);
                v[0] += qc * bf2f(qv.x); v[1] += qc * bf2f(qv.y);
                v[2] += qc * bf2f(qv.z); v[3] += qc * bf2f(qv.w);
            }
            ushort4 pk;
            pk.x = f2bf(v[0]); pk.y = f2bf(v[1]); pk.z = f2bf(v[2]); pk.w = f2bf(v[3]);
            *(ushort4*)(Oh + off) = pk;
        }
    }
}

// ================================================================ GEMM3 + fused output contraction
// Same direct-global K-loop; epilogue contracts with psi_emb/f_b, shfl-reduces
// over the 16 d-lanes, atomicAdds mw[h]*sum into out (zeroed by phase1).
__global__ __launch_bounds__(256) void gemm3_out(
    const short* __restrict__ At, const short* __restrict__ Bt,
    const short* __restrict__ Pt, const short* __restrict__ Qt,
    const float* __restrict__ psi_emb, const float* __restrict__ f_b,
    const float* __restrict__ head_mix, float* __restrict__ out)
{
    const int h = blockIdx.z;
    const short* Ah = At + (size_t)h * 1048576;
    const short* Bh = Bt + (size_t)h * 524288;
    const short* Ph = Pt + (size_t)h * 524288;
    const short* Qh = Qt + (size_t)h * 524288;

    const int c0 = blockIdx.x * 64;
    const int r0 = blockIdx.y * 64;
    const int tid = threadIdx.x;
    const int wave = tid >> 6, lane = tid & 63;
    const int q = lane >> 4, m16 = lane & 15;
    const int wr = wave >> 1, wc = wave & 1;

    __shared__ float es[64][17];
    {
        const int row = tid >> 2, dq = (tid & 3) * 4;
        const float4 ev = *(const float4*)(psi_emb + (size_t)(r0 + row) * DE + dq);
        es[row][dq] = ev.x; es[row][dq + 1] = ev.y;
        es[row][dq + 2] = ev.z; es[row][dq + 3] = ev.w;
    }
    __syncthreads();

    const short* Ap = Ah + (size_t)q * 8192 + (size_t)(r0 + wr * 32 + m16) * 8;
    const short* Bp = Bh + (size_t)q * 4096 + (size_t)(c0 + wc * 32 + m16) * 8;

    f32x4 acc[2][2];
#pragma unroll
    for (int mi = 0; mi < 2; mi++)
#pragma unroll
        for (int ni = 0; ni < 2; ni++) acc[mi][ni] = (f32x4){0.f, 0.f, 0.f, 0.f};

#pragma unroll 8
    for (int it = 0; it < 32; it++) {
        const bf16x8 af0 = *(const bf16x8*)(Ap + (size_t)it * 32768);
        const bf16x8 af1 = *(const bf16x8*)(Ap + (size_t)it * 32768 + 128);
        const bf16x8 bf0 = *(const bf16x8*)(Bp + (size_t)it * 16384);
        const bf16x8 bf1 = *(const bf16x8*)(Bp + (size_t)it * 16384 + 128);
        acc[0][0] = __builtin_amdgcn_mfma_f32_16x16x32_bf16(af0, bf0, acc[0][0], 0, 0, 0);
        acc[0][1] = __builtin_amdgcn_mfma_f32_16x16x32_bf16(af0, bf1, acc[0][1], 0, 0, 0);
        acc[1][0] = __builtin_amdgcn_mfma_f32_16x16x32_bf16(af1, bf0, acc[1][0], 0, 0, 0);
        acc[1][1] = __builtin_amdgcn_mfma_f32_16x16x32_bf16(af1, bf1, acc[1][1], 0, 0, 0);
    }

    const float hm0 = head_mix[0], hm1 = head_mix[1], hm2 = head_mix[2], hm3 = head_mix[3];
    const float mx = fmaxf(fmaxf(hm0, hm1), fmaxf(hm2, hm3));
    const float w0 = expf(hm0 - mx), w1 = expf(hm1 - mx), w2 = expf(hm2 - mx), w3 = expf(hm3 - mx);
    const float isum = 1.f / (w0 + w1 + w2 + w3);
    const float mwh = (h == 0 ? w0 : h == 1 ? w1 : h == 2 ? w2 : w3) * isum;
    const float fb = f_b[h * DE + m16];

#pragma unroll
    for (int mi = 0; mi < 2; mi++) {
        const int rloc0 = wr * 32 + mi * 16 + q * 4;
        const int row0 = r0 + rloc0;
#pragma unroll
        for (int ni = 0; ni < 2; ni++) {
            const int cc = c0 + wc * 32 + ni * 16 + m16;
            const int b = cc >> 4;
            const size_t off = ((size_t)(row0 >> 3) * 512 + cc) * 8 + (row0 & 7);
            const ushort4 pv = *(const ushort4*)(Ph + off);
            const ushort4 qv = *(const ushort4*)(Qh + off);
            float v[4];
            v[0] = acc[mi][ni][0] + bf2f(pv.x) - bf2f(qv.x);
            v[1] = acc[mi][ni][1] + bf2f(pv.y) - bf2f(qv.y);
            v[2] = acc[mi][ni][2] + bf2f(pv.z) - bf2f(qv.z);
            v[3] = acc[mi][ni][3] + bf2f(pv.w) - bf2f(qv.w);
#pragma unroll
            for (int r = 0; r < 4; r++) {
                float w = es[rloc0 + r][m16] * (v[r] + fb);
                w += __shfl_xor(w, 1, 64);
                w += __shfl_xor(w, 2, 64);
                w += __shfl_xor(w, 4, 64);
                w += __shfl_xor(w, 8, 64);
                if (m16 == 0)
                    atomicAdd(out + (size_t)b * NN + (row0 + r), mwh * w);
            }
        }
    }
}

extern "C" void kernel_launch(void* const* d_in, const int* in_sizes, int n_in,
                              void* d_out, int out_size, void* d_ws, size_t ws_size,
                              hipStream_t stream)
{
    const float* x          = (const float*)d_in[0];
    const float* psi_emb    = (const float*)d_in[1];
    const float* psi        = (const float*)d_in[2];
    const float* W_q        = (const float*)d_in[3];
    const float* W_k        = (const float*)d_in[4];
    const float* attn_alpha = (const float*)d_in[5];
    const float* F_w        = (const float*)d_in[6];
    const float* f_b        = (const float*)d_in[7];
    const float* head_mix   = (const float*)d_in[8];
    float* out = (float*)d_out;

    short* At  = (short*)d_ws;                 // 4,194,304 shorts (per-h 1,048,576)
    short* xt  = At + 4194304;                 // 4,194,304
    short* wtt = xt + 4194304;                 // 32,768
    short* Gt  = wtt + 32768;                  // 16 slabs (k*4+h) x 524,288 shorts
    short* b2t = Gt + 8388608;                 // 2,097,152
    short* b1t = b2t + 2097152;                // 2,097,152
    short* bnt = b1t + 2097152;                // 1,048,576
    short* ant = bnt + 1048576;                // 4,194,304
    float* partials = (float*)(ant + 4194304); // 81,920 fp32

    const size_t need_bytes =
        (size_t)(4194304 + 4194304 + 32768 + 8388608 + 2097152 + 2097152 + 1048576 + 4194304) * 2 +
        (size_t)81920 * 4;
    if (ws_size < need_bytes) return;

    phase1<<<800, 256, 0, stream>>>(psi_emb, psi, W_q, W_k, x, F_w,
                                    bnt, ant, partials, xt, wtt, out);
    phase2<<<1280, 256, 0, stream>>>(xt, wtt, Gt, bnt, ant, partials,
                                     attn_alpha, At);

    const dim3 gg(BD / 64, NN / 64, HH);
    // b2t = bf16(G2 + 2*A@G3)
    gemm_mf<<<gg, 256, 0, stream>>>(At, Gt + 12 * (size_t)524288, Gt + 8 * (size_t)524288,
                                    Gt /*unused*/, b2t, 2.f, 1.f, 0.f);
    // b1t = bf16(G1 + 2*A@b2 - G3)
    gemm_mf<<<gg, 256, 0, stream>>>(At, b2t, Gt + 4 * (size_t)524288,
                                    Gt + 12 * (size_t)524288, b1t, 2.f, 1.f, -1.f);
    // out += mw[h] * e·(G0 + A@b1 - b2 + fb)
    gemm3_out<<<gg, 256, 0, stream>>>(At, b1t, Gt, b2t, psi_emb, f_b, head_mix, out);
}

// Round 10
// 147.717 us; speedup vs baseline: 1.5082x; 1.0276x over previous
//
#include <hip/hip_runtime.h>
#include <cstdint>

#define NN 1024
#define BB 32
#define LL 128
#define DE 16
#define HH 4
#define K1 4
#define BD 512
#define NS 524288   // NN*BD elements per head slab

using bf16x8 = __attribute__((ext_vector_type(8))) short;
using f32x4  = __attribute__((ext_vector_type(4))) float;

__device__ inline unsigned short f2bf(float f) {
    unsigned u = __builtin_bit_cast(unsigned, f);
    u += 0x7FFFu + ((u >> 16) & 1u);          // round-to-nearest-even
    return (unsigned short)(u >> 16);
}
__device__ inline float bf2f(unsigned short u) {
    return __builtin_bit_cast(float, (unsigned)u << 16);
}

struct LogitsSmem {
    float ejs[64][17];
    float eis[64][17];
    float kjs[64][64];
    float qis[4][64][17];
    float part[4][5][64];
    float wq[1024];
    float wk[1024];
};
struct XtSmem { float xs[64][128]; };

// ================================================================ PHASE 1
// logits (256) | xt_cast (512) | wtt_cast (16) | zero-out (16) = 800 blocks.
__global__ __launch_bounds__(256) void phase1(
    const float* __restrict__ psi_emb, const float* __restrict__ psi_p,
    const float* __restrict__ W_q, const float* __restrict__ W_k,
    const float* __restrict__ x, const float* __restrict__ F_w,
    short* __restrict__ bnt, short* __restrict__ ant, float* __restrict__ partials,
    short* __restrict__ xt, short* __restrict__ wtt, float* __restrict__ out)
{
    __shared__ __align__(16) char smem_raw[sizeof(LogitsSmem)];
    const int bid = blockIdx.x;
    const int tid = threadIdx.x;

    if (bid < 256) {
        // ---------------- logits role (inline Q/K projection)
        LogitsSmem& S = *(LogitsSmem*)smem_raw;
        const int jb = bid & 15, ib = bid >> 4;
        const int i0 = ib * 64, j0 = jb * 64;
        {
            const int row = tid >> 2, dq = (tid & 3) * 4;
            const float4 vj = *(const float4*)(psi_emb + (j0 + row) * DE + dq);
            S.ejs[row][dq] = vj.x; S.ejs[row][dq + 1] = vj.y;
            S.ejs[row][dq + 2] = vj.z; S.ejs[row][dq + 3] = vj.w;
            const float4 vi = *(const float4*)(psi_emb + (i0 + row) * DE + dq);
            S.eis[row][dq] = vi.x; S.eis[row][dq + 1] = vi.y;
            S.eis[row][dq + 2] = vi.z; S.eis[row][dq + 3] = vi.w;
            *(float4*)&S.wq[tid * 4] = *(const float4*)(W_q + tid * 4);
            *(float4*)&S.wk[tid * 4] = *(const float4*)(W_k + tid * 4);
        }
        __syncthreads();
#pragma unroll
        for (int rep = 0; rep < 16; rep++) {
            const int idx = rep * 256 + tid;
            const int row = idx >> 6, hm = idx & 63;
            float qv = 0.f, kv = 0.f;
#pragma unroll
            for (int d = 0; d < DE; d++) {
                qv += S.eis[row][d] * S.wq[d * 64 + hm];
                kv += S.ejs[row][d] * S.wk[d * 64 + hm];
            }
            S.qis[hm >> 4][row][hm & 15] = qv;
            S.kjs[row][hm] = kv;
        }
        __syncthreads();

        const int i = tid & 63, jg = tid >> 6;
        const float psi = psi_p[0];
        float er[DE];
#pragma unroll
        for (int d = 0; d < DE; d++) er[d] = S.eis[i][d];

        float sb = 0.f, sa[HH] = {0.f, 0.f, 0.f, 0.f};
#pragma unroll
        for (int g = 0; g < 2; g++) {
            unsigned short bw[8];
#pragma unroll
            for (int r = 0; r < 8; r++) {
                const int j = jg * 16 + g * 8 + r;
                float d2 = 0.f;
#pragma unroll
                for (int d = 0; d < DE; d++) { const float t = er[d] - S.ejs[j][d]; d2 += t * t; }
                const float bn = __expf(__expf(-psi * d2));
                sb += bn;
                bw[r] = f2bf(bn);
            }
            uint4 pk;
            pk.x = bw[0] | ((unsigned)bw[1] << 16);
            pk.y = bw[2] | ((unsigned)bw[3] << 16);
            pk.z = bw[4] | ((unsigned)bw[5] << 16);
            pk.w = bw[6] | ((unsigned)bw[7] << 16);
            const size_t toff = (size_t)((j0 + jg * 16 + g * 8) >> 3) * 8192 + (size_t)(i0 + i) * 8;
            *(uint4*)(bnt + toff) = pk;
        }
#pragma unroll
        for (int h = 0; h < HH; h++) {
            float qr[DE];
#pragma unroll
            for (int m = 0; m < DE; m++) qr[m] = S.qis[h][i][m];
#pragma unroll
            for (int g = 0; g < 2; g++) {
                unsigned short aw[8];
#pragma unroll
                for (int r = 0; r < 8; r++) {
                    const int j = jg * 16 + g * 8 + r;
                    float dot = 0.f;
#pragma unroll
                    for (int m = 0; m < DE; m++) dot += qr[m] * S.kjs[j][h * DE + m];
                    const float an = __expf(dot * 0.25f);
                    sa[h] += an;
                    aw[r] = f2bf(an);
                }
                uint4 pk;
                pk.x = aw[0] | ((unsigned)aw[1] << 16);
                pk.y = aw[2] | ((unsigned)aw[3] << 16);
                pk.z = aw[4] | ((unsigned)aw[5] << 16);
                pk.w = aw[6] | ((unsigned)aw[7] << 16);
                const size_t toff = (size_t)((j0 + jg * 16 + g * 8) >> 3) * 8192 + (size_t)(i0 + i) * 8;
                *(uint4*)(ant + (size_t)h * 1048576 + toff) = pk;
            }
        }
        S.part[jg][0][i] = sb;
#pragma unroll
        for (int h = 0; h < HH; h++) S.part[jg][1 + h][i] = sa[h];
        __syncthreads();
        if (tid < 64) {
#pragma unroll
            for (int s = 0; s < 5; s++) {
                const float v = S.part[0][s][tid] + S.part[1][s][tid] +
                                S.part[2][s][tid] + S.part[3][s][tid];
                partials[(size_t)jb * 5120 + (size_t)s * 1024 + i0 + tid] = v;
            }
        }
    } else if (bid < 768) {
        // ---------------- xt_cast role
        XtSmem& X = *(XtSmem*)smem_raw;
        const int idx = bid - 256;
        const int m0 = (idx & 15) * 64;
        const int b  = idx >> 4;
        for (int i = tid; i < 2048; i += 256) {
            const int row = i >> 5, lq = i & 31;
            *(float4*)&X.xs[row][lq * 4] =
                *(const float4*)(x + ((size_t)(b * NN + m0 + row)) * LL + lq * 4);
        }
        __syncthreads();
        for (int j = tid; j < 1024; j += 256) {
            const int m = j & 63, lc = j >> 6;
            const float* s = &X.xs[m][lc * 8];
            uint4 pk;
            pk.x = f2bf(s[0]) | ((unsigned)f2bf(s[1]) << 16);
            pk.y = f2bf(s[2]) | ((unsigned)f2bf(s[3]) << 16);
            pk.z = f2bf(s[4]) | ((unsigned)f2bf(s[5]) << 16);
            pk.w = f2bf(s[6]) | ((unsigned)f2bf(s[7]) << 16);
            *(uint4*)(xt + (size_t)b * 131072 + (size_t)lc * 8192 + (size_t)(m0 + m) * 8) = pk;
        }
    } else if (bid < 784) {
        // ---------------- wtt_cast role
        const int j = (bid - 768) * 256 + tid;
        const int lc = j >> 8, c = j & 255;
        const int h = c >> 6, k = (c >> 4) & 3, d = c & 15;
        const float* s = F_w + (size_t)((h * DE + d) * K1 + k) * LL + lc * 8;
        uint4 pk;
        pk.x = f2bf(s[0]) | ((unsigned)f2bf(s[1]) << 16);
        pk.y = f2bf(s[2]) | ((unsigned)f2bf(s[3]) << 16);
        pk.z = f2bf(s[4]) | ((unsigned)f2bf(s[5]) << 16);
        pk.w = f2bf(s[6]) | ((unsigned)f2bf(s[7]) << 16);
        *(uint4*)(wtt + (size_t)lc * 2048 + (size_t)c * 8) = pk;
    } else {
        // ---------------- zero-out role (out is poisoned 0xAA each launch)
        const int idx = (bid - 784) * 256 + tid;       // 4096 threads, 8 floats each
        const float4 z = {0.f, 0.f, 0.f, 0.f};
        *(float4*)(out + (size_t)idx * 8) = z;
        *(float4*)(out + (size_t)idx * 8 + 4) = z;
    }
}

// ================================================================ PHASE 2
// g_mfma (1024 blocks, all-bf16 tiled Gt output) + blend (256 blocks).
__global__ __launch_bounds__(256) void phase2(
    const short* __restrict__ xt, const short* __restrict__ wtt,
    short* __restrict__ Gt,
    const short* __restrict__ bnt, const short* __restrict__ ant,
    const float* __restrict__ partials, const float* __restrict__ alpha_p,
    short* __restrict__ At)
{
    const int bid = blockIdx.x;
    const int tid = threadIdx.x;
    __shared__ float sums_l[5][64];

    if (bid < 1024) {
        // ---------------- g_mfma role
        const int cb = bid & 3;
        const int m0 = ((bid >> 2) & 15) * 64;
        const int bp = bid >> 6;
        const int wave = tid >> 6, lane = tid & 63;
        const int b  = bp * 2 + (wave >> 1);
        const int wc = wave & 1;
        const int q = lane >> 4, m16 = lane & 15;
        const short* xb = xt + (size_t)b * 131072;

        f32x4 acc[4][2];
#pragma unroll
        for (int mi = 0; mi < 4; mi++)
#pragma unroll
            for (int ni = 0; ni < 2; ni++) acc[mi][ni] = (f32x4){0.f, 0.f, 0.f, 0.f};

#pragma unroll
        for (int ks = 0; ks < 4; ks++) {
            const int kc = ks * 4 + q;
            bf16x8 a[4], bb[2];
#pragma unroll
            for (int mi = 0; mi < 4; mi++)
                a[mi] = *(const bf16x8*)(xb + (size_t)kc * 8192 + (size_t)(m0 + mi * 16 + m16) * 8);
#pragma unroll
            for (int ni = 0; ni < 2; ni++)
                bb[ni] = *(const bf16x8*)(wtt + (size_t)kc * 2048 +
                                          (size_t)(cb * 64 + wc * 32 + ni * 16 + m16) * 8);
#pragma unroll
            for (int mi = 0; mi < 4; mi++)
#pragma unroll
                for (int ni = 0; ni < 2; ni++)
                    acc[mi][ni] = __builtin_amdgcn_mfma_f32_16x16x32_bf16(a[mi], bb[ni], acc[mi][ni], 0, 0, 0);
        }

        // bf16 tiled stores only (full-line coalesced); slab = kk*4+hh
#pragma unroll
        for (int ni = 0; ni < 2; ni++) {
            const int cc = cb * 64 + wc * 32 + ni * 16 + m16;
            const int kk = (cc >> 4) & 3, hh = cc >> 6;
            const int col512 = b * 16 + (cc & 15);
            short* gdst = Gt + (size_t)(kk * 4 + hh) * 524288;
#pragma unroll
            for (int mi = 0; mi < 4; mi++) {
                const int row0 = m0 + mi * 16 + q * 4;
                ushort4 pk;
                pk.x = f2bf(acc[mi][ni][0]); pk.y = f2bf(acc[mi][ni][1]);
                pk.z = f2bf(acc[mi][ni][2]); pk.w = f2bf(acc[mi][ni][3]);
                *(ushort4*)(gdst + ((size_t)(row0 >> 3) * 512 + col512) * 8 + (row0 & 7)) = pk;
            }
        }
    } else {
        // ---------------- blend role
        const int idx = bid - 1024;
        const int jb = idx & 15, ib = idx >> 4;
        const int i0 = ib * 64, j0 = jb * 64;
        const int lane = tid & 63, w = tid >> 6;
        {
            float acc = 0.f;
#pragma unroll
            for (int jb2 = 0; jb2 < 16; jb2++)
                acc += partials[(size_t)jb2 * 5120 + (size_t)w * 1024 + i0 + lane];
            sums_l[w][lane] = acc;
            if (w == 0) {
                float a4 = 0.f;
#pragma unroll
                for (int jb2 = 0; jb2 < 16; jb2++)
                    a4 += partials[(size_t)jb2 * 5120 + 4 * 1024 + i0 + lane];
                sums_l[4][lane] = a4;
            }
        }
        __syncthreads();
        const int i = lane, jg = w;
        const float alpha = 1.f / (1.f + __expf(-alpha_p[0]));
        const float ibs = alpha / sums_l[0][i];
        float ias[HH];
#pragma unroll
        for (int h = 0; h < HH; h++) ias[h] = (1.f - alpha) / sums_l[1 + h][i];

#pragma unroll
        for (int g = 0; g < 2; g++) {
            const size_t toff = (size_t)((j0 + jg * 16 + g * 8) >> 3) * 8192 + (size_t)(i0 + i) * 8;
            const uint4 bp = *(const uint4*)(bnt + toff);
            float bnv[8];
            bnv[0] = bf2f(bp.x & 0xFFFF); bnv[1] = bf2f(bp.x >> 16);
            bnv[2] = bf2f(bp.y & 0xFFFF); bnv[3] = bf2f(bp.y >> 16);
            bnv[4] = bf2f(bp.z & 0xFFFF); bnv[5] = bf2f(bp.z >> 16);
            bnv[6] = bf2f(bp.w & 0xFFFF); bnv[7] = bf2f(bp.w >> 16);
#pragma unroll
            for (int h = 0; h < HH; h++) {
                const uint4 ap = *(const uint4*)(ant + (size_t)h * 1048576 + toff);
                float av[8];
                av[0] = bf2f(ap.x & 0xFFFF); av[1] = bf2f(ap.x >> 16);
                av[2] = bf2f(ap.y & 0xFFFF); av[3] = bf2f(ap.y >> 16);
                av[4] = bf2f(ap.z & 0xFFFF); av[5] = bf2f(ap.z >> 16);
                av[6] = bf2f(ap.w & 0xFFFF); av[7] = bf2f(ap.w >> 16);
                unsigned short ow[8];
#pragma unroll
                for (int r = 0; r < 8; r++) ow[r] = f2bf(ibs * bnv[r] + ias[h] * av[r]);
                uint4 pk;
                pk.x = ow[0] | ((unsigned)ow[1] << 16);
                pk.y = ow[2] | ((unsigned)ow[3] << 16);
                pk.z = ow[4] | ((unsigned)ow[5] << 16);
                pk.w = ow[6] | ((unsigned)ow[7] << 16);
                *(uint4*)(At + (size_t)h * 1048576 + toff) = pk;
            }
        }
    }
}

// ================================================================ Clenshaw GEMM (MFMA, direct-global fragments)
// R9 post-mortem: LDS->direct-global was near-neutral; both bound by A/B cache
// traffic. With z-major grids each XCD's L2 (4 MB) sees all 4 heads (12 MB
// working set) -> L3-serviced. XCD-affinity swizzle: round-robin bid%8 means
// bids {2h,2h+1} land on a fixed XCD pair -> per-XCD working set 3 MB, fits L2.
__global__ __launch_bounds__(256) void gemm_mf(
    const short* __restrict__ At, const short* __restrict__ Bt,
    const short* __restrict__ Pt, const short* __restrict__ Qt,
    short* __restrict__ Ot, float scale, float pc, float qc)
{
    const int bid = blockIdx.x;                        // 512 blocks, 1D
    const int h = (bid & 7) >> 1;                      // XCD-pair affinity
    const int tile = ((bid >> 3) << 1) | (bid & 1);    // 0..127
    const int c0 = (tile & 7) * 64;
    const int r0 = (tile >> 3) * 64;

    const short* Ah = At + (size_t)h * 1048576;
    const short* Bh = Bt + (size_t)h * 524288;
    const short* Ph = Pt + (size_t)h * 524288;
    const short* Qh = Qt + (size_t)h * 524288;
    short* Oh = Ot + (size_t)h * 524288;

    const int tid = threadIdx.x;
    const int wave = tid >> 6, lane = tid & 63;
    const int q = lane >> 4, m16 = lane & 15;
    const int wr = wave >> 1, wc = wave & 1;

    const short* Ap = Ah + (size_t)q * 8192 + (size_t)(r0 + wr * 32 + m16) * 8;
    const short* Bp = Bh + (size_t)q * 4096 + (size_t)(c0 + wc * 32 + m16) * 8;

    f32x4 acc[2][2];
#pragma unroll
    for (int mi = 0; mi < 2; mi++)
#pragma unroll
        for (int ni = 0; ni < 2; ni++) acc[mi][ni] = (f32x4){0.f, 0.f, 0.f, 0.f};

#pragma unroll 8
    for (int it = 0; it < 32; it++) {
        const bf16x8 af0 = *(const bf16x8*)(Ap + (size_t)it * 32768);
        const bf16x8 af1 = *(const bf16x8*)(Ap + (size_t)it * 32768 + 128);
        const bf16x8 bf0 = *(const bf16x8*)(Bp + (size_t)it * 16384);
        const bf16x8 bf1 = *(const bf16x8*)(Bp + (size_t)it * 16384 + 128);
        acc[0][0] = __builtin_amdgcn_mfma_f32_16x16x32_bf16(af0, bf0, acc[0][0], 0, 0, 0);
        acc[0][1] = __builtin_amdgcn_mfma_f32_16x16x32_bf16(af0, bf1, acc[0][1], 0, 0, 0);
        acc[1][0] = __builtin_amdgcn_mfma_f32_16x16x32_bf16(af1, bf0, acc[1][0], 0, 0, 0);
        acc[1][1] = __builtin_amdgcn_mfma_f32_16x16x32_bf16(af1, bf1, acc[1][1], 0, 0, 0);
    }

#pragma unroll
    for (int mi = 0; mi < 2; mi++) {
        const int row0 = r0 + wr * 32 + mi * 16 + q * 4;
#pragma unroll
        for (int ni = 0; ni < 2; ni++) {
            const int cc = c0 + wc * 32 + ni * 16 + m16;
            const size_t off = ((size_t)(row0 >> 3) * 512 + cc) * 8 + (row0 & 7);
            const ushort4 pv = *(const ushort4*)(Ph + off);
            float v[4];
            v[0] = scale * acc[mi][ni][0] + pc * bf2f(pv.x);
            v[1] = scale * acc[mi][ni][1] + pc * bf2f(pv.y);
            v[2] = scale * acc[mi][ni][2] + pc * bf2f(pv.z);
            v[3] = scale * acc[mi][ni][3] + pc * bf2f(pv.w);
            if (qc != 0.f) {
                const ushort4 qv = *(const ushort4*)(Qh + off);
                v[0] += qc * bf2f(qv.x); v[1] += qc * bf2f(qv.y);
                v[2] += qc * bf2f(qv.z); v[3] += qc * bf2f(qv.w);
            }
            ushort4 pk;
            pk.x = f2bf(v[0]); pk.y = f2bf(v[1]); pk.z = f2bf(v[2]); pk.w = f2bf(v[3]);
            *(ushort4*)(Oh + off) = pk;
        }
    }
}

// ================================================================ GEMM3 + fused output contraction
// Same XCD-affinity 1D grid; epilogue contracts with psi_emb/f_b, shfl-reduces
// over the 16 d-lanes, atomicAdds mw[h]*sum into out (zeroed by phase1).
__global__ __launch_bounds__(256) void gemm3_out(
    const short* __restrict__ At, const short* __restrict__ Bt,
    const short* __restrict__ Pt, const short* __restrict__ Qt,
    const float* __restrict__ psi_emb, const float* __restrict__ f_b,
    const float* __restrict__ head_mix, float* __restrict__ out)
{
    const int bid = blockIdx.x;                        // 512 blocks, 1D
    const int h = (bid & 7) >> 1;
    const int tile = ((bid >> 3) << 1) | (bid & 1);
    const int c0 = (tile & 7) * 64;
    const int r0 = (tile >> 3) * 64;

    const short* Ah = At + (size_t)h * 1048576;
    const short* Bh = Bt + (size_t)h * 524288;
    const short* Ph = Pt + (size_t)h * 524288;
    const short* Qh = Qt + (size_t)h * 524288;

    const int tid = threadIdx.x;
    const int wave = tid >> 6, lane = tid & 63;
    const int q = lane >> 4, m16 = lane & 15;
    const int wr = wave >> 1, wc = wave & 1;

    __shared__ float es[64][17];
    {
        const int row = tid >> 2, dq = (tid & 3) * 4;
        const float4 ev = *(const float4*)(psi_emb + (size_t)(r0 + row) * DE + dq);
        es[row][dq] = ev.x; es[row][dq + 1] = ev.y;
        es[row][dq + 2] = ev.z; es[row][dq + 3] = ev.w;
    }
    __syncthreads();

    const short* Ap = Ah + (size_t)q * 8192 + (size_t)(r0 + wr * 32 + m16) * 8;
    const short* Bp = Bh + (size_t)q * 4096 + (size_t)(c0 + wc * 32 + m16) * 8;

    f32x4 acc[2][2];
#pragma unroll
    for (int mi = 0; mi < 2; mi++)
#pragma unroll
        for (int ni = 0; ni < 2; ni++) acc[mi][ni] = (f32x4){0.f, 0.f, 0.f, 0.f};

#pragma unroll 8
    for (int it = 0; it < 32; it++) {
        const bf16x8 af0 = *(const bf16x8*)(Ap + (size_t)it * 32768);
        const bf16x8 af1 = *(const bf16x8*)(Ap + (size_t)it * 32768 + 128);
        const bf16x8 bf0 = *(const bf16x8*)(Bp + (size_t)it * 16384);
        const bf16x8 bf1 = *(const bf16x8*)(Bp + (size_t)it * 16384 + 128);
        acc[0][0] = __builtin_amdgcn_mfma_f32_16x16x32_bf16(af0, bf0, acc[0][0], 0, 0, 0);
        acc[0][1] = __builtin_amdgcn_mfma_f32_16x16x32_bf16(af0, bf1, acc[0][1], 0, 0, 0);
        acc[1][0] = __builtin_amdgcn_mfma_f32_16x16x32_bf16(af1, bf0, acc[1][0], 0, 0, 0);
        acc[1][1] = __builtin_amdgcn_mfma_f32_16x16x32_bf16(af1, bf1, acc[1][1], 0, 0, 0);
    }

    const float hm0 = head_mix[0], hm1 = head_mix[1], hm2 = head_mix[2], hm3 = head_mix[3];
    const float mx = fmaxf(fmaxf(hm0, hm1), fmaxf(hm2, hm3));
    const float w0 = expf(hm0 - mx), w1 = expf(hm1 - mx), w2 = expf(hm2 - mx), w3 = expf(hm3 - mx);
    const float isum = 1.f / (w0 + w1 + w2 + w3);
    const float mwh = (h == 0 ? w0 : h == 1 ? w1 : h == 2 ? w2 : w3) * isum;
    const float fb = f_b[h * DE + m16];

#pragma unroll
    for (int mi = 0; mi < 2; mi++) {
        const int rloc0 = wr * 32 + mi * 16 + q * 4;
        const int row0 = r0 + rloc0;
#pragma unroll
        for (int ni = 0; ni < 2; ni++) {
            const int cc = c0 + wc * 32 + ni * 16 + m16;
            const int b = cc >> 4;
            const size_t off = ((size_t)(row0 >> 3) * 512 + cc) * 8 + (row0 & 7);
            const ushort4 pv = *(const ushort4*)(Ph + off);
            const ushort4 qv = *(const ushort4*)(Qh + off);
            float v[4];
            v[0] = acc[mi][ni][0] + bf2f(pv.x) - bf2f(qv.x);
            v[1] = acc[mi][ni][1] + bf2f(pv.y) - bf2f(qv.y);
            v[2] = acc[mi][ni][2] + bf2f(pv.z) - bf2f(qv.z);
            v[3] = acc[mi][ni][3] + bf2f(pv.w) - bf2f(qv.w);
#pragma unroll
            for (int r = 0; r < 4; r++) {
                float w = es[rloc0 + r][m16] * (v[r] + fb);
                w += __shfl_xor(w, 1, 64);
                w += __shfl_xor(w, 2, 64);
                w += __shfl_xor(w, 4, 64);
                w += __shfl_xor(w, 8, 64);
                if (m16 == 0)
                    atomicAdd(out + (size_t)b * NN + (row0 + r), mwh * w);
            }
        }
    }
}

extern "C" void kernel_launch(void* const* d_in, const int* in_sizes, int n_in,
                              void* d_out, int out_size, void* d_ws, size_t ws_size,
                              hipStream_t stream)
{
    const float* x          = (const float*)d_in[0];
    const float* psi_emb    = (const float*)d_in[1];
    const float* psi        = (const float*)d_in[2];
    const float* W_q        = (const float*)d_in[3];
    const float* W_k        = (const float*)d_in[4];
    const float* attn_alpha = (const float*)d_in[5];
    const float* F_w        = (const float*)d_in[6];
    const float* f_b        = (const float*)d_in[7];
    const float* head_mix   = (const float*)d_in[8];
    float* out = (float*)d_out;

    short* At  = (short*)d_ws;                 // 4,194,304 shorts (per-h 1,048,576)
    short* xt  = At + 4194304;                 // 4,194,304
    short* wtt = xt + 4194304;                 // 32,768
    short* Gt  = wtt + 32768;                  // 16 slabs (k*4+h) x 524,288 shorts
    short* b2t = Gt + 8388608;                 // 2,097,152
    short* b1t = b2t + 2097152;                // 2,097,152
    short* bnt = b1t + 2097152;                // 1,048,576
    short* ant = bnt + 1048576;                // 4,194,304
    float* partials = (float*)(ant + 4194304); // 81,920 fp32

    const size_t need_bytes =
        (size_t)(4194304 + 4194304 + 32768 + 8388608 + 2097152 + 2097152 + 1048576 + 4194304) * 2 +
        (size_t)81920 * 4;
    if (ws_size < need_bytes) return;

    phase1<<<800, 256, 0, stream>>>(psi_emb, psi, W_q, W_k, x, F_w,
                                    bnt, ant, partials, xt, wtt, out);
    phase2<<<1280, 256, 0, stream>>>(xt, wtt, Gt, bnt, ant, partials,
                                     attn_alpha, At);

    // b2t = bf16(G2 + 2*A@G3)
    gemm_mf<<<512, 256, 0, stream>>>(At, Gt + 12 * (size_t)524288, Gt + 8 * (size_t)524288,
                                     Gt /*unused*/, b2t, 2.f, 1.f, 0.f);
    // b1t = bf16(G1 + 2*A@b2 - G3)
    gemm_mf<<<512, 256, 0, stream>>>(At, b2t, Gt + 4 * (size_t)524288,
                                     Gt + 12 * (size_t)524288, b1t, 2.f, 1.f, -1.f);
    // out += mw[h] * e·(G0 + A@b1 - b2 + fb)
    gemm3_out<<<512, 256, 0, stream>>>(At, b1t, Gt, b2t, psi_emb, f_b, head_mix, out);
}